// Round 1
// baseline (675.592 us; speedup 1.0000x reference)
//
#include <hip/hip_runtime.h>

// ---------------------------------------------------------------------------
// SegmentwiseInterpretableMultiHeadAttention — Round 1: fp32 correctness base
// B=2 Lq=1024 Lkv=2048 D=1024 H=16 dk=dv=64 SEG=256 nseg=8 L=8192
// d_out = [outputs (2*8192*1024)] ++ [attn_out (2*8192*16*256)]
// ws: qs[2,16,1024,64] kp[2,16,2048,64] vp[2,2048,64] mh[2,8,1024,64] ~30MB
// ---------------------------------------------------------------------------

#define B_ 2
#define LQ 1024
#define LKV 2048
#define D_ 1024
#define H_ 16
#define DK 64
#define SEGW 256
#define NSEG 8
#define LTOT 8192  // NSEG*LQ

// ------------- projection GEMM: C[b,h,m,:] = A[b,m,:] @ W[h] + bias[h] ------
// A: [B_*Mb, D_]  W: [nH, D_, DK]  bias: [nH, DK]
// C: [((b*nH + h)*Mb + m)*DK + n]
__global__ __launch_bounds__(256) void proj_kernel(
    const float* __restrict__ A, const float* __restrict__ W,
    const float* __restrict__ bias, float* __restrict__ C,
    int Mb, int nH)
{
  __shared__ __align__(16) float AsT[16][68];  // [k][row]
  __shared__ __align__(16) float Ws[16][68];   // [k][n]
  const int h   = blockIdx.y;
  const int gr0 = blockIdx.x * 64;
  const int tid = threadIdx.x;
  const int tx = tid & 15, ty = tid >> 4;
  const float* Wp = W + (size_t)h * (D_ * DK);

  float acc[4][4];
#pragma unroll
  for (int i = 0; i < 4; ++i)
#pragma unroll
    for (int j = 0; j < 4; ++j) acc[i][j] = 0.f;

  const int lrow = tid >> 2, lf4 = tid & 3;   // A-tile loader
  const int lkw = tid >> 4, ln4 = tid & 15;   // W-tile loader

  for (int k0 = 0; k0 < D_; k0 += 16) {
    float4 a = *(const float4*)(A + (size_t)(gr0 + lrow) * D_ + k0 + lf4 * 4);
    AsT[lf4 * 4 + 0][lrow] = a.x;
    AsT[lf4 * 4 + 1][lrow] = a.y;
    AsT[lf4 * 4 + 2][lrow] = a.z;
    AsT[lf4 * 4 + 3][lrow] = a.w;
    *(float4*)&Ws[lkw][ln4 * 4] =
        *(const float4*)(Wp + (size_t)(k0 + lkw) * DK + ln4 * 4);
    __syncthreads();
#pragma unroll
    for (int kk = 0; kk < 16; ++kk) {
      float4 a4 = *(const float4*)&AsT[kk][ty * 4];
      float4 b4 = *(const float4*)&Ws[kk][tx * 4];
      float av[4] = {a4.x, a4.y, a4.z, a4.w};
      float bv[4] = {b4.x, b4.y, b4.z, b4.w};
#pragma unroll
      for (int i = 0; i < 4; ++i)
#pragma unroll
        for (int j = 0; j < 4; ++j)
          acc[i][j] = fmaf(av[i], bv[j], acc[i][j]);
    }
    __syncthreads();
  }

  float4 bb = *(const float4*)(bias + (size_t)h * DK + tx * 4);
#pragma unroll
  for (int i = 0; i < 4; ++i) {
    int grow = gr0 + ty * 4 + i;
    int b = grow / Mb;
    int m = grow - b * Mb;
    float4 o;
    o.x = acc[i][0] + bb.x;
    o.y = acc[i][1] + bb.y;
    o.z = acc[i][2] + bb.z;
    o.w = acc[i][3] + bb.w;
    *(float4*)(C + ((size_t)(b * nH + h) * Mb + m) * DK + tx * 4) = o;
  }
}

// ------------- scores + softmax -> attn_out --------------------------------
// qs: [B_,H_,LQ,DK]   kp: [B_,H_,LKV,DK]
// attn_out[b, l=n*LQ+q, h, s], 32 q-rows per block; kp segment in LDS
// (XOR-swizzled float4 units -> conflict-free ds_read_b128)
__global__ __launch_bounds__(256) void attn_sm_kernel(
    const float* __restrict__ qs, const float* __restrict__ kp,
    float* __restrict__ attn_out)
{
  __shared__ __align__(16) float qsL[32][68];
  __shared__ __align__(16) float kpL[256][64];
  const int qt = blockIdx.x;   // 0..31
  const int n  = blockIdx.y;   // 0..7
  const int bh = blockIdx.z;   // 0..31 (b*16+h)
  const int b = bh >> 4, h = bh & 15;
  const int tid = threadIdx.x;

  {
    int row = tid >> 3, f4b = tid & 7;
    const float* qp = qs + ((size_t)bh * LQ + qt * 32 + row) * DK;
#pragma unroll
    for (int jj = 0; jj < 2; ++jj) {
      int f4 = f4b + jj * 8;
      *(float4*)&qsL[row][f4 * 4] = *(const float4*)(qp + f4 * 4);
    }
  }
  {
    int f4 = tid & 15, s0 = tid >> 4;
    const float* kpn = kp + ((size_t)bh * LKV + n * SEGW) * DK;
#pragma unroll
    for (int i = 0; i < 16; ++i) {
      int s = s0 + i * 16;  // s>>4 == i
      float4 vv = *(const float4*)(kpn + (size_t)s * DK + f4 * 4);
      *(float4*)&kpL[s][(f4 ^ i) * 4] = vv;
    }
  }
  __syncthreads();

  const int r0 = tid >> 4;  // rows r0 and r0+16
  const int sg = tid & 15;  // s-group: s = sg*16 .. sg*16+15
  float sc[2][16];
#pragma unroll
  for (int i = 0; i < 2; ++i)
#pragma unroll
    for (int j = 0; j < 16; ++j) sc[i][j] = 0.f;

#pragma unroll
  for (int d4 = 0; d4 < 16; ++d4) {
    float4 qa = *(const float4*)&qsL[r0][d4 * 4];
    float4 qb = *(const float4*)&qsL[r0 + 16][d4 * 4];
    const int u = (d4 ^ sg) * 4;  // matches store swizzle: s>>4 == sg here
#pragma unroll
    for (int j = 0; j < 16; ++j) {
      float4 k4 = *(const float4*)&kpL[sg * 16 + j][u];
      sc[0][j] += qa.x * k4.x + qa.y * k4.y + qa.z * k4.z + qa.w * k4.w;
      sc[1][j] += qb.x * k4.x + qb.y * k4.y + qb.z * k4.z + qb.w * k4.w;
    }
  }

#pragma unroll
  for (int i = 0; i < 2; ++i) {
    const int row = r0 + i * 16;
    const int q = qt * 32 + row;  // global q in 0..1023
    float m = -3.0e38f;
#pragma unroll
    for (int j = 0; j < 16; ++j) {
      int s = sg * 16 + j;
      float vv = sc[i][j] * 0.125f;      // / sqrt(dk)=8
      if (s > q) vv = -1.0e9f;           // same causal mask every segment
      sc[i][j] = vv;
      m = fmaxf(m, vv);
    }
    m = fmaxf(m, __shfl_xor(m, 1));
    m = fmaxf(m, __shfl_xor(m, 2));
    m = fmaxf(m, __shfl_xor(m, 4));
    m = fmaxf(m, __shfl_xor(m, 8));
    float sum = 0.f;
#pragma unroll
    for (int j = 0; j < 16; ++j) {
      sc[i][j] = __expf(sc[i][j] - m);
      sum += sc[i][j];
    }
    sum += __shfl_xor(sum, 1);
    sum += __shfl_xor(sum, 2);
    sum += __shfl_xor(sum, 4);
    sum += __shfl_xor(sum, 8);
    const float inv = 1.0f / sum;
    float* op = attn_out +
        (((size_t)b * LTOT + (size_t)n * LQ + q) * H_ + h) * SEGW + sg * 16;
#pragma unroll
    for (int j4 = 0; j4 < 4; ++j4) {
      float4 o;
      o.x = sc[i][j4 * 4 + 0] * inv;
      o.y = sc[i][j4 * 4 + 1] * inv;
      o.z = sc[i][j4 * 4 + 2] * inv;
      o.w = sc[i][j4 * 4 + 3] * inv;
      *(float4*)(op + j4 * 4) = o;
    }
  }
}

// ------------- PV + mean over heads -> mh[b,n,q,dv] ------------------------
// reads attn_out (from d_out) and vp [B_, LKV, DK]; 32 q-rows per block
__global__ __launch_bounds__(256) void pv_kernel(
    const float* __restrict__ attn_out, const float* __restrict__ vp,
    float* __restrict__ mh)
{
  __shared__ __align__(16) float vpL[64][68];  // [s_in_chunk][dv]
  __shared__ __align__(16) float PsT[64][36];  // [s_in_chunk][qrow]
  const int q0 = blockIdx.x * 32;
  const int n  = blockIdx.y;
  const int b  = blockIdx.z;
  const int tid = threadIdx.x;
  const int tx = tid & 15, ty = tid >> 4;

  float acc[2][4];
#pragma unroll
  for (int i = 0; i < 2; ++i)
#pragma unroll
    for (int j = 0; j < 4; ++j) acc[i][j] = 0.f;

  for (int c = 0; c < 4; ++c) {   // s-chunks of 64
    __syncthreads();
    {
      int s = tid >> 2, f4b = tid & 3;
      const float* vpp = vp + ((size_t)b * LKV + n * SEGW + c * 64 + s) * DK;
#pragma unroll
      for (int jj = 0; jj < 4; ++jj) {
        int f4 = f4b + jj * 4;
        *(float4*)&vpL[s][f4 * 4] = *(const float4*)(vpp + f4 * 4);
      }
    }
    for (int hh = 0; hh < H_; ++hh) {
      __syncthreads();
      {
        int qrow = tid >> 3, f4b = tid & 7;
        const float* pp = attn_out +
            (((size_t)b * LTOT + (size_t)n * LQ + q0 + qrow) * H_ + hh) * SEGW +
            c * 64;
#pragma unroll
        for (int jj = 0; jj < 2; ++jj) {
          int f4 = f4b + jj * 8;
          float4 vv = *(const float4*)(pp + f4 * 4);
          PsT[f4 * 4 + 0][qrow] = vv.x;
          PsT[f4 * 4 + 1][qrow] = vv.y;
          PsT[f4 * 4 + 2][qrow] = vv.z;
          PsT[f4 * 4 + 3][qrow] = vv.w;
        }
      }
      __syncthreads();
#pragma unroll 16
      for (int kk = 0; kk < 64; ++kk) {
        float a0 = PsT[kk][ty * 2 + 0];
        float a1 = PsT[kk][ty * 2 + 1];
        float4 b4 = *(const float4*)&vpL[kk][tx * 4];
        float bv[4] = {b4.x, b4.y, b4.z, b4.w};
#pragma unroll
        for (int j = 0; j < 4; ++j) {
          acc[0][j] = fmaf(a0, bv[j], acc[0][j]);
          acc[1][j] = fmaf(a1, bv[j], acc[1][j]);
        }
      }
    }
  }

  const float s16 = 1.0f / 16.0f;
#pragma unroll
  for (int i = 0; i < 2; ++i) {
    int qq = q0 + ty * 2 + i;
    float4 o;
    o.x = acc[i][0] * s16;
    o.y = acc[i][1] * s16;
    o.z = acc[i][2] * s16;
    o.w = acc[i][3] * s16;
    *(float4*)(mh + (((size_t)b * NSEG + n) * LQ + qq) * DK + tx * 4) = o;
  }
}

// ------------- final: outputs = mh @ Wh  ([B_*LTOT,64] @ [64,1024]) --------
__global__ __launch_bounds__(256) void final_kernel(
    const float* __restrict__ mh, const float* __restrict__ Wh,
    float* __restrict__ outputs)
{
  __shared__ __align__(16) float mhT[64][68];  // [k][row]
  __shared__ __align__(16) float WhL[64][68];  // [k][col]
  const int r0 = blockIdx.x * 64;
  const int c0 = blockIdx.y * 64;
  const int tid = threadIdx.x;
  const int tx = tid & 15, ty = tid >> 4;

  {
    int row = tid >> 2, f4b = tid & 3;
    const float* mp = mh + (size_t)(r0 + row) * DK;
#pragma unroll
    for (int jj = 0; jj < 4; ++jj) {
      int f4 = f4b + jj * 4;
      float4 vv = *(const float4*)(mp + f4 * 4);
      mhT[f4 * 4 + 0][row] = vv.x;
      mhT[f4 * 4 + 1][row] = vv.y;
      mhT[f4 * 4 + 2][row] = vv.z;
      mhT[f4 * 4 + 3][row] = vv.w;
    }
    int kk = tid >> 2;
    const float* wp = Wh + (size_t)kk * D_ + c0;
#pragma unroll
    for (int jj = 0; jj < 4; ++jj) {
      int f4 = f4b + jj * 4;
      *(float4*)&WhL[kk][f4 * 4] = *(const float4*)(wp + f4 * 4);
    }
  }
  __syncthreads();

  float acc[4][4];
#pragma unroll
  for (int i = 0; i < 4; ++i)
#pragma unroll
    for (int j = 0; j < 4; ++j) acc[i][j] = 0.f;

#pragma unroll 8
  for (int kk = 0; kk < 64; ++kk) {
    float4 a4 = *(const float4*)&mhT[kk][ty * 4];
    float4 b4 = *(const float4*)&WhL[kk][tx * 4];
    float av[4] = {a4.x, a4.y, a4.z, a4.w};
    float bv[4] = {b4.x, b4.y, b4.z, b4.w};
#pragma unroll
    for (int i = 0; i < 4; ++i)
#pragma unroll
      for (int j = 0; j < 4; ++j)
        acc[i][j] = fmaf(av[i], bv[j], acc[i][j]);
  }

#pragma unroll
  for (int i = 0; i < 4; ++i) {
    float4 o;
    o.x = acc[i][0];
    o.y = acc[i][1];
    o.z = acc[i][2];
    o.w = acc[i][3];
    *(float4*)(outputs + (size_t)(r0 + ty * 4 + i) * D_ + c0 + tx * 4) = o;
  }
}

// ---------------------------------------------------------------------------
extern "C" void kernel_launch(void* const* d_in, const int* in_sizes, int n_in,
                              void* d_out, int out_size, void* d_ws,
                              size_t ws_size, hipStream_t stream) {
  const float* q  = (const float*)d_in[0];
  const float* k  = (const float*)d_in[1];
  const float* v  = (const float*)d_in[2];
  const float* Wq = (const float*)d_in[3];
  const float* bq = (const float*)d_in[4];
  const float* Wk = (const float*)d_in[5];
  const float* bk = (const float*)d_in[6];
  const float* Wv = (const float*)d_in[7];
  const float* bv = (const float*)d_in[8];
  const float* Wh = (const float*)d_in[9];

  float* outputs  = (float*)d_out;                            // [B_,LTOT,D_]
  float* attn_out = (float*)d_out + (size_t)B_ * LTOT * D_;   // [B_,LTOT,H_,SEGW]

  float* ws = (float*)d_ws;
  float* qs = ws;                                    // [B_,H_,LQ,DK]
  float* kp = qs + (size_t)B_ * H_ * LQ * DK;        // [B_,H_,LKV,DK]
  float* vp = kp + (size_t)B_ * H_ * LKV * DK;       // [B_,LKV,DK]
  float* mh = vp + (size_t)B_ * LKV * DK;            // [B_,NSEG,LQ,DK]

  hipLaunchKernelGGL(proj_kernel, dim3(B_ * LQ / 64, H_), dim3(256), 0, stream,
                     q, Wq, bq, qs, LQ, H_);
  hipLaunchKernelGGL(proj_kernel, dim3(B_ * LKV / 64, H_), dim3(256), 0, stream,
                     k, Wk, bk, kp, LKV, H_);
  hipLaunchKernelGGL(proj_kernel, dim3(B_ * LKV / 64, 1), dim3(256), 0, stream,
                     v, Wv, bv, vp, LKV, 1);
  hipLaunchKernelGGL(attn_sm_kernel, dim3(LQ / 32, NSEG, B_ * H_), dim3(256), 0,
                     stream, qs, kp, attn_out);
  hipLaunchKernelGGL(pv_kernel, dim3(LQ / 32, NSEG, B_), dim3(256), 0, stream,
                     attn_out, vp, mh);
  hipLaunchKernelGGL(final_kernel, dim3(B_ * LTOT / 64, D_ / 64), dim3(256), 0,
                     stream, mh, Wh, outputs);
}

// Round 2
// 442.394 us; speedup vs baseline: 1.5271x; 1.5271x over previous
//
#include <hip/hip_runtime.h>

// ---------------------------------------------------------------------------
// Round 2: bf16-MFMA pipeline with split-precision (hi/lo) q/k path.
// B=2 Lq=1024 Lkv=2048 D=1024 H=16 dk=dv=64 SEG=256 nseg=8 L=8192
// d_out = [outputs (2*8192*1024) f32] ++ [attn_out (2*8192*16*256) f32]
// ---------------------------------------------------------------------------

#define B_ 2
#define LQ 1024
#define LKV 2048
#define D_ 1024
#define H_ 16
#define DK 64
#define SEGW 256
#define NSEG 8
#define LTOT 8192

typedef __attribute__((ext_vector_type(8))) short bf16x8;
typedef __attribute__((ext_vector_type(4))) float f32x4;
typedef __attribute__((ext_vector_type(4))) unsigned short us4;

__device__ __forceinline__ unsigned short f2bf(float x) {
  unsigned int u = __float_as_uint(x);
  u = (u + 0x7fffu + ((u >> 16) & 1u)) >> 16;
  return (unsigned short)u;
}
__device__ __forceinline__ float bf2f(unsigned short h) {
  return __uint_as_float(((unsigned int)h) << 16);
}

#define MFMA16(a, b, c) __builtin_amdgcn_mfma_f32_16x16x32_bf16((a), (b), (c), 0, 0, 0)

// ---------------- prep: W[h][d][n] -> WT[(h*N+n)][d] split hi/lo bf16 -------
__global__ __launch_bounds__(256) void transpose_split_kernel(
    const float* __restrict__ src, unsigned short* __restrict__ hi,
    unsigned short* __restrict__ lo, int D, int N) {
  __shared__ float T[32][33];
  const int d0 = blockIdx.x * 32, n0 = blockIdx.y * 32, h = blockIdx.z;
  const float* sp = src + (size_t)h * D * N;
  const int c = threadIdx.x & 31, r0 = threadIdx.x >> 5;
#pragma unroll
  for (int i = 0; i < 4; ++i) {
    int r = r0 + i * 8;
    T[r][c] = sp[(size_t)(d0 + r) * N + n0 + c];
  }
  __syncthreads();
#pragma unroll
  for (int i = 0; i < 4; ++i) {
    int rr = r0 + i * 8;         // n-dim
    float v = T[c][rr];          // src[d0+c][n0+rr]
    size_t idx = (size_t)(h * N + n0 + rr) * D + d0 + c;
    unsigned short hh = f2bf(v);
    hi[idx] = hh;
    lo[idx] = f2bf(v - bf2f(hh));
  }
}

// ---------------- proj (split): C = A[M,1024] @ Wcat[1024,1024] + bias ------
// WT_hi/lo: [c][k] row-major along k. Output: C_hi/lo [m][c] bf16 split.
__global__ __launch_bounds__(256) void proj_split_kernel(
    const float* __restrict__ A, const unsigned short* __restrict__ WT_hi,
    const unsigned short* __restrict__ WT_lo, const float* __restrict__ bias,
    unsigned short* __restrict__ C_hi, unsigned short* __restrict__ C_lo) {
  __shared__ unsigned short Ahi[128][40], Alo[128][40];
  __shared__ unsigned short Bhi[128][40], Blo[128][40];
  const int m0 = blockIdx.x * 128, c0 = blockIdx.y * 128;
  const int tid = threadIdx.x, lane = tid & 63, w = tid >> 6;
  const int wr = w >> 1, wc = w & 1;
  const int l15 = lane & 15, l4 = lane >> 4;

  f32x4 acc[4][4];
#pragma unroll
  for (int i = 0; i < 4; ++i)
#pragma unroll
    for (int j = 0; j < 4; ++j) acc[i][j] = (f32x4)0.f;

  for (int k0 = 0; k0 < 1024; k0 += 32) {
    __syncthreads();
    {
      int f4 = tid & 7, row0 = tid >> 3;
#pragma unroll
      for (int p = 0; p < 4; ++p) {
        int r = row0 + p * 32;
        float4 a = *(const float4*)(A + (size_t)(m0 + r) * 1024 + k0 + f4 * 4);
        us4 h4, l4v;
        h4.x = f2bf(a.x); l4v.x = f2bf(a.x - bf2f(h4.x));
        h4.y = f2bf(a.y); l4v.y = f2bf(a.y - bf2f(h4.y));
        h4.z = f2bf(a.z); l4v.z = f2bf(a.z - bf2f(h4.z));
        h4.w = f2bf(a.w); l4v.w = f2bf(a.w - bf2f(h4.w));
        *(us4*)&Ahi[r][f4 * 4] = h4;
        *(us4*)&Alo[r][f4 * 4] = l4v;
      }
      int u = tid & 3, cb = tid >> 2;
#pragma unroll
      for (int p = 0; p < 2; ++p) {
        int cc = cb + p * 64;
        size_t gi = (size_t)(c0 + cc) * 1024 + k0 + u * 8;
        *(bf16x8*)&Bhi[cc][u * 8] = *(const bf16x8*)(WT_hi + gi);
        *(bf16x8*)&Blo[cc][u * 8] = *(const bf16x8*)(WT_lo + gi);
      }
    }
    __syncthreads();
    bf16x8 ah[4], al[4], bh[4], bl[4];
#pragma unroll
    for (int i = 0; i < 4; ++i) {
      ah[i] = *(const bf16x8*)&Ahi[wr * 64 + i * 16 + l15][l4 * 8];
      al[i] = *(const bf16x8*)&Alo[wr * 64 + i * 16 + l15][l4 * 8];
      bh[i] = *(const bf16x8*)&Bhi[wc * 64 + i * 16 + l15][l4 * 8];
      bl[i] = *(const bf16x8*)&Blo[wc * 64 + i * 16 + l15][l4 * 8];
    }
#pragma unroll
    for (int i = 0; i < 4; ++i)
#pragma unroll
      for (int j = 0; j < 4; ++j) {
        acc[i][j] = MFMA16(ah[i], bh[j], acc[i][j]);
        acc[i][j] = MFMA16(ah[i], bl[j], acc[i][j]);
        acc[i][j] = MFMA16(al[i], bh[j], acc[i][j]);
      }
  }

#pragma unroll
  for (int j = 0; j < 4; ++j) {
    int c = c0 + wc * 64 + j * 16 + l15;
    float bs = bias[c];
#pragma unroll
    for (int i = 0; i < 4; ++i) {
      int m = m0 + wr * 64 + i * 16 + l4 * 4;
#pragma unroll
      for (int r = 0; r < 4; ++r) {
        float v = acc[i][j][r] + bs;
        unsigned short hh = f2bf(v);
        C_hi[(size_t)(m + r) * 1024 + c] = hh;
        C_lo[(size_t)(m + r) * 1024 + c] = f2bf(v - bf2f(hh));
      }
    }
  }
}

// ---------------- v-proj (plain bf16): vpT_g[b][n][dv][s] ------------------
__global__ __launch_bounds__(256) void vproj_kernel(
    const float* __restrict__ v, const unsigned short* __restrict__ WvT_hi,
    const float* __restrict__ bv, unsigned short* __restrict__ vpTg) {
  __shared__ unsigned short Av[64][40], Bv[64][40];
  const int m0 = blockIdx.x * 64;
  const int tid = threadIdx.x, lane = tid & 63, w = tid >> 6;
  const int l15 = lane & 15, l4 = lane >> 4;

  f32x4 acc[4];
#pragma unroll
  for (int j = 0; j < 4; ++j) acc[j] = (f32x4)0.f;

  for (int k0 = 0; k0 < 1024; k0 += 32) {
    __syncthreads();
    {
      int f4 = tid & 7, row0 = tid >> 3;
#pragma unroll
      for (int p = 0; p < 2; ++p) {
        int r = row0 + p * 32;
        float4 a = *(const float4*)(v + (size_t)(m0 + r) * 1024 + k0 + f4 * 4);
        us4 h4;
        h4.x = f2bf(a.x); h4.y = f2bf(a.y); h4.z = f2bf(a.z); h4.w = f2bf(a.w);
        *(us4*)&Av[r][f4 * 4] = h4;
      }
      int u = tid & 3, cb = tid >> 2;
      *(bf16x8*)&Bv[cb][u * 8] =
          *(const bf16x8*)(WvT_hi + (size_t)cb * 1024 + k0 + u * 8);
    }
    __syncthreads();
    bf16x8 a8 = *(const bf16x8*)&Av[w * 16 + l15][l4 * 8];
#pragma unroll
    for (int cf = 0; cf < 4; ++cf) {
      bf16x8 b8 = *(const bf16x8*)&Bv[cf * 16 + l15][l4 * 8];
      acc[cf] = MFMA16(a8, b8, acc[cf]);
    }
  }
  const int m = m0 + w * 16 + l4 * 4;
  const int b = m >> 11, sg = m & 2047, n = sg >> 8, si = sg & 255;
#pragma unroll
  for (int cf = 0; cf < 4; ++cf) {
    int dv = cf * 16 + l15;
    float bvv = bv[dv];
    us4 o;
    o.x = f2bf(acc[cf][0] + bvv);
    o.y = f2bf(acc[cf][1] + bvv);
    o.z = f2bf(acc[cf][2] + bvv);
    o.w = f2bf(acc[cf][3] + bvv);
    *(us4*)(vpTg + ((size_t)((b * 8 + n) * 64 + dv)) * 256 + si) = o;
  }
}

// ---------------- fused: scores(split) + softmax + attn_out + PV + mean ----
__global__ __launch_bounds__(256) void fused_attn_kernel(
    const unsigned short* __restrict__ qs_hi, const unsigned short* __restrict__ qs_lo,
    const unsigned short* __restrict__ kp_hi, const unsigned short* __restrict__ kp_lo,
    const unsigned short* __restrict__ vpTg, float* __restrict__ attn_out,
    float* __restrict__ mh) {
  __shared__ unsigned short Khi[256][72];   // P_lds overlays this (33792<=36864)
  __shared__ unsigned short Klo[256][72];
  __shared__ unsigned short Qhi[64][72], Qlo[64][72];
  __shared__ unsigned short vpT[64][264];
  unsigned short(*P_lds)[264] = (unsigned short(*)[264]) & Khi[0][0];

  // XCD-aware decode: 16 q-tiles of one (b,n) share one XCD's L2.
  const int lin = blockIdx.x;
  const int xcd = lin & 7, slot = lin >> 3;
  const int pair = xcd * 2 + (slot >> 4);
  const int b = pair >> 3, n = pair & 7, qt = slot & 15;
  const int q0 = qt * 64;

  const int tid = threadIdx.x, lane = tid & 63, w = tid >> 6;
  const int l15 = lane & 15, l4 = lane >> 4;

  // stage vpT once: [64][256] bf16 contiguous per (b,n)
  {
    const unsigned short* src = vpTg + ((size_t)(b * 8 + n) * 64) * 256;
    int dv = tid >> 2, u0 = tid & 3;
#pragma unroll
    for (int i = 0; i < 8; ++i) {
      int u = u0 + i * 4;
      *(bf16x8*)&vpT[dv][u * 8] = *(const bf16x8*)(src + dv * 256 + u * 8);
    }
  }

  f32x4 accO[4];
#pragma unroll
  for (int j = 0; j < 4; ++j) accO[j] = (f32x4)0.f;

  for (int h = 0; h < H_; ++h) {
    __syncthreads();
    {  // stage K segment (hi/lo)
      int u = tid & 7, s0 = tid >> 3;
#pragma unroll
      for (int p = 0; p < 8; ++p) {
        int s = s0 + p * 32;
        size_t gi = (size_t)(b * 2048 + n * 256 + s) * 1024 + h * 64 + u * 8;
        *(bf16x8*)&Khi[s][u * 8] = *(const bf16x8*)(kp_hi + gi);
        *(bf16x8*)&Klo[s][u * 8] = *(const bf16x8*)(kp_lo + gi);
      }
      // stage Q tile (hi/lo)
      int r = tid >> 2, ub = (tid & 3) * 2;
#pragma unroll
      for (int i = 0; i < 2; ++i) {
        int u = ub + i;
        size_t gi = (size_t)(b * 1024 + q0 + r) * 1024 + h * 64 + u * 8;
        *(bf16x8*)&Qhi[r][u * 8] = *(const bf16x8*)(qs_hi + gi);
        *(bf16x8*)&Qlo[r][u * 8] = *(const bf16x8*)(qs_lo + gi);
      }
    }
    __syncthreads();

    // scores: S[64q x 256s], wave w owns q rows w*16..w*16+15
    f32x4 accS[16];
#pragma unroll
    for (int sf = 0; sf < 16; ++sf) accS[sf] = (f32x4)0.f;
#pragma unroll
    for (int kc = 0; kc < 2; ++kc) {
      bf16x8 ahi = *(const bf16x8*)&Qhi[w * 16 + l15][kc * 32 + l4 * 8];
      bf16x8 alo = *(const bf16x8*)&Qlo[w * 16 + l15][kc * 32 + l4 * 8];
#pragma unroll
      for (int sf = 0; sf < 16; ++sf) {
        bf16x8 bhi = *(const bf16x8*)&Khi[sf * 16 + l15][kc * 32 + l4 * 8];
        bf16x8 blo = *(const bf16x8*)&Klo[sf * 16 + l15][kc * 32 + l4 * 8];
        accS[sf] = MFMA16(ahi, bhi, accS[sf]);
        accS[sf] = MFMA16(ahi, blo, accS[sf]);
        accS[sf] = MFMA16(alo, bhi, accS[sf]);
      }
    }

    // softmax (rows fp32-accurate); mask s>q, scale 1/8
    float inv[4];
#pragma unroll
    for (int r = 0; r < 4; ++r) {
      const int qg = q0 + w * 16 + l4 * 4 + r;
      float mx = -3.0e38f;
#pragma unroll
      for (int sf = 0; sf < 16; ++sf) {
        int s = sf * 16 + l15;
        float vv = accS[sf][r] * 0.125f;
        if (s > qg) vv = -3.0e38f;
        accS[sf][r] = vv;
        mx = fmaxf(mx, vv);
      }
      mx = fmaxf(mx, __shfl_xor(mx, 1));
      mx = fmaxf(mx, __shfl_xor(mx, 2));
      mx = fmaxf(mx, __shfl_xor(mx, 4));
      mx = fmaxf(mx, __shfl_xor(mx, 8));
      float sum = 0.f;
#pragma unroll
      for (int sf = 0; sf < 16; ++sf) {
        float e = __expf(accS[sf][r] - mx);
        accS[sf][r] = e;
        sum += e;
      }
      sum += __shfl_xor(sum, 1);
      sum += __shfl_xor(sum, 2);
      sum += __shfl_xor(sum, 4);
      sum += __shfl_xor(sum, 8);
      inv[r] = 1.0f / sum;
    }

    __syncthreads();  // all K reads done before P overlays K
#pragma unroll
    for (int r = 0; r < 4; ++r)
#pragma unroll
      for (int sf = 0; sf < 16; ++sf)
        P_lds[w * 16 + l4 * 4 + r][sf * 16 + l15] = f2bf(accS[sf][r] * inv[r]);
    __syncthreads();

    // attn_out from P_lds (coalesced), P rounded to bf16 (abs err <= 2e-3)
    {
      int qr = tid >> 2, ck = tid & 3;
      float* op = attn_out +
          ((((size_t)b * LTOT + (size_t)n * LQ + q0 + qr) * H_ + h) * SEGW) + ck * 64;
#pragma unroll
      for (int u = 0; u < 8; ++u) {
        bf16x8 p8 = *(const bf16x8*)&P_lds[qr][ck * 64 + u * 8];
        float4 f0, f1;
        f0.x = bf2f((unsigned short)p8[0]); f0.y = bf2f((unsigned short)p8[1]);
        f0.z = bf2f((unsigned short)p8[2]); f0.w = bf2f((unsigned short)p8[3]);
        f1.x = bf2f((unsigned short)p8[4]); f1.y = bf2f((unsigned short)p8[5]);
        f1.z = bf2f((unsigned short)p8[6]); f1.w = bf2f((unsigned short)p8[7]);
        *(float4*)(op + u * 8) = f0;
        *(float4*)(op + u * 8 + 4) = f1;
      }
    }

    // PV: accO += P(64x256) @ vpT^T(256x64)
#pragma unroll
    for (int kc = 0; kc < 8; ++kc) {
      bf16x8 pa = *(const bf16x8*)&P_lds[w * 16 + l15][kc * 32 + l4 * 8];
#pragma unroll
      for (int vf = 0; vf < 4; ++vf) {
        bf16x8 b8 = *(const bf16x8*)&vpT[vf * 16 + l15][kc * 32 + l4 * 8];
        accO[vf] = MFMA16(pa, b8, accO[vf]);
      }
    }
  }

  const float s16 = 1.0f / 16.0f;
#pragma unroll
  for (int vf = 0; vf < 4; ++vf)
#pragma unroll
    for (int r = 0; r < 4; ++r)
      mh[((size_t)((b * 8 + n) * 1024) + q0 + w * 16 + l4 * 4 + r) * 64 + vf * 16 +
         l15] = accO[vf][r] * s16;
}

// ---------------- final: outputs = mh[16384,64] @ Wh[64,1024] --------------
__global__ __launch_bounds__(256) void final_mfma_kernel(
    const float* __restrict__ mh, const unsigned short* __restrict__ WhT_hi,
    float* __restrict__ outputs) {
  __shared__ unsigned short Af[64][72], Bf[128][72];
  const int m0 = blockIdx.x * 64, c0 = blockIdx.y * 128;
  const int tid = threadIdx.x, lane = tid & 63, w = tid >> 6;
  const int l15 = lane & 15, l4 = lane >> 4;
  {
    int f4 = tid & 15, row0 = tid >> 4;
#pragma unroll
    for (int p = 0; p < 4; ++p) {
      int r = row0 + p * 16;
      float4 a = *(const float4*)(mh + (size_t)(m0 + r) * 64 + f4 * 4);
      us4 h4;
      h4.x = f2bf(a.x); h4.y = f2bf(a.y); h4.z = f2bf(a.z); h4.w = f2bf(a.w);
      *(us4*)&Af[r][f4 * 4] = h4;
    }
    int u = tid & 7, cb = tid >> 3;
#pragma unroll
    for (int p = 0; p < 4; ++p) {
      int c = cb + p * 32;
      *(bf16x8*)&Bf[c][u * 8] =
          *(const bf16x8*)(WhT_hi + (size_t)(c0 + c) * 64 + u * 8);
    }
  }
  __syncthreads();

  f32x4 acc[8];
#pragma unroll
  for (int cf = 0; cf < 8; ++cf) acc[cf] = (f32x4)0.f;
#pragma unroll
  for (int kc = 0; kc < 2; ++kc) {
    bf16x8 a8 = *(const bf16x8*)&Af[w * 16 + l15][kc * 32 + l4 * 8];
#pragma unroll
    for (int cf = 0; cf < 8; ++cf) {
      bf16x8 b8 = *(const bf16x8*)&Bf[cf * 16 + l15][kc * 32 + l4 * 8];
      acc[cf] = MFMA16(a8, b8, acc[cf]);
    }
  }
#pragma unroll
  for (int cf = 0; cf < 8; ++cf)
#pragma unroll
    for (int r = 0; r < 4; ++r)
      outputs[(size_t)(m0 + w * 16 + l4 * 4 + r) * 1024 + c0 + cf * 16 + l15] =
          acc[cf][r];
}

// ---------------------------------------------------------------------------
extern "C" void kernel_launch(void* const* d_in, const int* in_sizes, int n_in,
                              void* d_out, int out_size, void* d_ws,
                              size_t ws_size, hipStream_t stream) {
  const float* q  = (const float*)d_in[0];
  const float* k  = (const float*)d_in[1];
  const float* v  = (const float*)d_in[2];
  const float* Wq = (const float*)d_in[3];
  const float* bq = (const float*)d_in[4];
  const float* Wk = (const float*)d_in[5];
  const float* bk = (const float*)d_in[6];
  const float* Wv = (const float*)d_in[7];
  const float* bv = (const float*)d_in[8];
  const float* Wh = (const float*)d_in[9];

  float* outputs  = (float*)d_out;
  float* attn_out = (float*)d_out + (size_t)B_ * LTOT * D_;

  char* ws = (char*)d_ws;
  // layout (bytes); mh overlays WqT (dead after proj-q)
  unsigned short* WqT_hi = (unsigned short*)(ws + 0);            // 2MB
  unsigned short* WqT_lo = (unsigned short*)(ws + (2u << 20));   // 2MB
  float*          mh     = (float*)(ws + 0);                     // 4MB overlay
  unsigned short* WkT_hi = (unsigned short*)(ws + (4u << 20));   // 2MB
  unsigned short* WkT_lo = (unsigned short*)(ws + (6u << 20));   // 2MB
  unsigned short* WvT_hi = (unsigned short*)(ws + (8u << 20));           // 128KB
  unsigned short* WvT_lo = (unsigned short*)(ws + (8u << 20) + 131072);  // 128KB
  unsigned short* WhT_hi = (unsigned short*)(ws + (8u << 20) + 262144);  // 128KB
  unsigned short* WhT_lo = (unsigned short*)(ws + (8u << 20) + 393216);  // 128KB
  unsigned short* qs_hi  = (unsigned short*)(ws + (8u << 20) + 524288);  // 4MB
  unsigned short* qs_lo  = (unsigned short*)((char*)qs_hi + (4u << 20));
  unsigned short* kp_hi  = (unsigned short*)((char*)qs_lo + (4u << 20));  // 8MB
  unsigned short* kp_lo  = (unsigned short*)((char*)kp_hi + (8u << 20));  // 8MB
  unsigned short* vpTg   = (unsigned short*)((char*)kp_lo + (8u << 20));  // 512KB

  transpose_split_kernel<<<dim3(32, 2, 16), 256, 0, stream>>>(Wq, WqT_hi, WqT_lo, 1024, 64);
  transpose_split_kernel<<<dim3(32, 2, 16), 256, 0, stream>>>(Wk, WkT_hi, WkT_lo, 1024, 64);
  transpose_split_kernel<<<dim3(32, 2, 1), 256, 0, stream>>>(Wv, WvT_hi, WvT_lo, 1024, 64);
  transpose_split_kernel<<<dim3(2, 32, 1), 256, 0, stream>>>(Wh, WhT_hi, WhT_lo, 64, 1024);

  proj_split_kernel<<<dim3(16, 8), 256, 0, stream>>>(q, WqT_hi, WqT_lo, bq, qs_hi, qs_lo);
  proj_split_kernel<<<dim3(32, 8), 256, 0, stream>>>(k, WkT_hi, WkT_lo, bk, kp_hi, kp_lo);
  vproj_kernel<<<dim3(64), 256, 0, stream>>>(v, WvT_hi, bv, vpTg);

  fused_attn_kernel<<<dim3(256), 256, 0, stream>>>(qs_hi, qs_lo, kp_hi, kp_lo,
                                                   vpTg, attn_out, mh);
  final_mfma_kernel<<<dim3(256, 8), 256, 0, stream>>>(mh, WhT_hi, outputs);
}

// Round 3
// 436.123 us; speedup vs baseline: 1.5491x; 1.0144x over previous
//
#include <hip/hip_runtime.h>

// ---------------------------------------------------------------------------
// Round 3: occupancy-focused fused attention.
// - No K/Q/V LDS staging (direct L2 fragment loads), P_lds only (34 KB)
// - Head-group split x4 (grid 1024), bf16 partial mh buffers
// - Non-temporal attn_out / outputs stores
// B=2 Lq=1024 Lkv=2048 D=1024 H=16 dk=dv=64 SEG=256 nseg=8 L=8192
// ---------------------------------------------------------------------------

#define B_ 2
#define LQ 1024
#define LKV 2048
#define D_ 1024
#define H_ 16
#define DK 64
#define SEGW 256
#define NSEG 8
#define LTOT 8192

typedef __attribute__((ext_vector_type(8))) short bf16x8;
typedef __attribute__((ext_vector_type(4))) float f32x4;
typedef __attribute__((ext_vector_type(4))) unsigned short us4;

__device__ __forceinline__ unsigned short f2bf(float x) {
  unsigned int u = __float_as_uint(x);
  u = (u + 0x7fffu + ((u >> 16) & 1u)) >> 16;
  return (unsigned short)u;
}
__device__ __forceinline__ float bf2f(unsigned short h) {
  return __uint_as_float(((unsigned int)h) << 16);
}

#define MFMA16(a, b, c) __builtin_amdgcn_mfma_f32_16x16x32_bf16((a), (b), (c), 0, 0, 0)

// ---------------- prep: W[h][d][n] -> WT[(h*N+n)][d] split hi/lo bf16 -------
__global__ __launch_bounds__(256) void transpose_split_kernel(
    const float* __restrict__ src, unsigned short* __restrict__ hi,
    unsigned short* __restrict__ lo, int D, int N) {
  __shared__ float T[32][33];
  const int d0 = blockIdx.x * 32, n0 = blockIdx.y * 32, h = blockIdx.z;
  const float* sp = src + (size_t)h * D * N;
  const int c = threadIdx.x & 31, r0 = threadIdx.x >> 5;
#pragma unroll
  for (int i = 0; i < 4; ++i) {
    int r = r0 + i * 8;
    T[r][c] = sp[(size_t)(d0 + r) * N + n0 + c];
  }
  __syncthreads();
#pragma unroll
  for (int i = 0; i < 4; ++i) {
    int rr = r0 + i * 8;         // n-dim
    float v = T[c][rr];          // src[d0+c][n0+rr]
    size_t idx = (size_t)(h * N + n0 + rr) * D + d0 + c;
    unsigned short hh = f2bf(v);
    hi[idx] = hh;
    lo[idx] = f2bf(v - bf2f(hh));
  }
}

// ---------------- proj (split): C = A[M,1024] @ Wcat[1024,1024] + bias ------
__global__ __launch_bounds__(256) void proj_split_kernel(
    const float* __restrict__ A, const unsigned short* __restrict__ WT_hi,
    const unsigned short* __restrict__ WT_lo, const float* __restrict__ bias,
    unsigned short* __restrict__ C_hi, unsigned short* __restrict__ C_lo) {
  __shared__ unsigned short Ahi[128][40], Alo[128][40];
  __shared__ unsigned short Bhi[128][40], Blo[128][40];
  const int m0 = blockIdx.x * 128, c0 = blockIdx.y * 128;
  const int tid = threadIdx.x, lane = tid & 63, w = tid >> 6;
  const int wr = w >> 1, wc = w & 1;
  const int l15 = lane & 15, l4 = lane >> 4;

  f32x4 acc[4][4];
#pragma unroll
  for (int i = 0; i < 4; ++i)
#pragma unroll
    for (int j = 0; j < 4; ++j) acc[i][j] = (f32x4)0.f;

  for (int k0 = 0; k0 < 1024; k0 += 32) {
    __syncthreads();
    {
      int f4 = tid & 7, row0 = tid >> 3;
#pragma unroll
      for (int p = 0; p < 4; ++p) {
        int r = row0 + p * 32;
        float4 a = *(const float4*)(A + (size_t)(m0 + r) * 1024 + k0 + f4 * 4);
        us4 h4, l4v;
        h4.x = f2bf(a.x); l4v.x = f2bf(a.x - bf2f(h4.x));
        h4.y = f2bf(a.y); l4v.y = f2bf(a.y - bf2f(h4.y));
        h4.z = f2bf(a.z); l4v.z = f2bf(a.z - bf2f(h4.z));
        h4.w = f2bf(a.w); l4v.w = f2bf(a.w - bf2f(h4.w));
        *(us4*)&Ahi[r][f4 * 4] = h4;
        *(us4*)&Alo[r][f4 * 4] = l4v;
      }
      int u = tid & 3, cb = tid >> 2;
#pragma unroll
      for (int p = 0; p < 2; ++p) {
        int cc = cb + p * 64;
        size_t gi = (size_t)(c0 + cc) * 1024 + k0 + u * 8;
        *(bf16x8*)&Bhi[cc][u * 8] = *(const bf16x8*)(WT_hi + gi);
        *(bf16x8*)&Blo[cc][u * 8] = *(const bf16x8*)(WT_lo + gi);
      }
    }
    __syncthreads();
    bf16x8 ah[4], al[4], bh[4], bl[4];
#pragma unroll
    for (int i = 0; i < 4; ++i) {
      ah[i] = *(const bf16x8*)&Ahi[wr * 64 + i * 16 + l15][l4 * 8];
      al[i] = *(const bf16x8*)&Alo[wr * 64 + i * 16 + l15][l4 * 8];
      bh[i] = *(const bf16x8*)&Bhi[wc * 64 + i * 16 + l15][l4 * 8];
      bl[i] = *(const bf16x8*)&Blo[wc * 64 + i * 16 + l15][l4 * 8];
    }
#pragma unroll
    for (int i = 0; i < 4; ++i)
#pragma unroll
      for (int j = 0; j < 4; ++j) {
        acc[i][j] = MFMA16(ah[i], bh[j], acc[i][j]);
        acc[i][j] = MFMA16(ah[i], bl[j], acc[i][j]);
        acc[i][j] = MFMA16(al[i], bh[j], acc[i][j]);
      }
  }

#pragma unroll
  for (int j = 0; j < 4; ++j) {
    int c = c0 + wc * 64 + j * 16 + l15;
    float bs = bias[c];
#pragma unroll
    for (int i = 0; i < 4; ++i) {
      int m = m0 + wr * 64 + i * 16 + l4 * 4;
#pragma unroll
      for (int r = 0; r < 4; ++r) {
        float v = acc[i][j][r] + bs;
        unsigned short hh = f2bf(v);
        C_hi[(size_t)(m + r) * 1024 + c] = hh;
        C_lo[(size_t)(m + r) * 1024 + c] = f2bf(v - bf2f(hh));
      }
    }
  }
}

// ---------------- v-proj (plain bf16): vpT_g[b][n][dv][s] ------------------
__global__ __launch_bounds__(256) void vproj_kernel(
    const float* __restrict__ v, const unsigned short* __restrict__ WvT_hi,
    const float* __restrict__ bv, unsigned short* __restrict__ vpTg) {
  __shared__ unsigned short Av[64][40], Bv[64][40];
  const int m0 = blockIdx.x * 64;
  const int tid = threadIdx.x, lane = tid & 63, w = tid >> 6;
  const int l15 = lane & 15, l4 = lane >> 4;

  f32x4 acc[4];
#pragma unroll
  for (int j = 0; j < 4; ++j) acc[j] = (f32x4)0.f;

  for (int k0 = 0; k0 < 1024; k0 += 32) {
    __syncthreads();
    {
      int f4 = tid & 7, row0 = tid >> 3;
#pragma unroll
      for (int p = 0; p < 2; ++p) {
        int r = row0 + p * 32;
        float4 a = *(const float4*)(v + (size_t)(m0 + r) * 1024 + k0 + f4 * 4);
        us4 h4;
        h4.x = f2bf(a.x); h4.y = f2bf(a.y); h4.z = f2bf(a.z); h4.w = f2bf(a.w);
        *(us4*)&Av[r][f4 * 4] = h4;
      }
      int u = tid & 3, cb = tid >> 2;
      *(bf16x8*)&Bv[cb][u * 8] =
          *(const bf16x8*)(WvT_hi + (size_t)cb * 1024 + k0 + u * 8);
    }
    __syncthreads();
    bf16x8 a8 = *(const bf16x8*)&Av[w * 16 + l15][l4 * 8];
#pragma unroll
    for (int cf = 0; cf < 4; ++cf) {
      bf16x8 b8 = *(const bf16x8*)&Bv[cf * 16 + l15][l4 * 8];
      acc[cf] = MFMA16(a8, b8, acc[cf]);
    }
  }
  const int m = m0 + w * 16 + l4 * 4;
  const int b = m >> 11, sg = m & 2047, n = sg >> 8, si = sg & 255;
#pragma unroll
  for (int cf = 0; cf < 4; ++cf) {
    int dv = cf * 16 + l15;
    float bvv = bv[dv];
    us4 o;
    o.x = f2bf(acc[cf][0] + bvv);
    o.y = f2bf(acc[cf][1] + bvv);
    o.z = f2bf(acc[cf][2] + bvv);
    o.w = f2bf(acc[cf][3] + bvv);
    *(us4*)(vpTg + ((size_t)((b * 8 + n) * 64 + dv)) * 256 + si) = o;
  }
}

// ---------------- fused: scores(split) + softmax + attn_out + PV -----------
// grid 1024: each block = (b, n, head-group of 4, q-tile of 64 rows)
__global__ __launch_bounds__(256, 3) void fused_attn_kernel(
    const unsigned short* __restrict__ qs_hi, const unsigned short* __restrict__ qs_lo,
    const unsigned short* __restrict__ kp_hi, const unsigned short* __restrict__ kp_lo,
    const unsigned short* __restrict__ vpTg, float* __restrict__ attn_out,
    unsigned short* __restrict__ mhp) {
  __shared__ unsigned short P_lds[64][264];

  const int lin = blockIdx.x;
  const int xcd = lin & 7, slot = lin >> 3;
  const int combo = xcd * 8 + (slot >> 4);  // 0..63
  const int qt = slot & 15;
  const int hg = combo >> 4;                // 0..3
  const int pair = combo & 15;              // b*8+n
  const int b = pair >> 3, n = pair & 7;
  const int q0 = qt * 64;

  const int tid = threadIdx.x, lane = tid & 63, w = tid >> 6;
  const int l15 = lane & 15, l4 = lane >> 4;

  f32x4 accO[4];
#pragma unroll
  for (int vf = 0; vf < 4; ++vf) accO[vf] = (f32x4)0.f;

  const unsigned short* vbase = vpTg + (size_t)pair * 64 * 256;

#pragma unroll 1
  for (int hh = 0; hh < 4; ++hh) {
    const int h = hg * 4 + hh;

    // Q A-fragments: direct global (L2)
    const size_t qoff =
        (size_t)(b * 1024 + q0 + w * 16 + l15) * 1024 + h * 64 + l4 * 8;
    bf16x8 ahi0 = *(const bf16x8*)(qs_hi + qoff);
    bf16x8 ahi1 = *(const bf16x8*)(qs_hi + qoff + 32);
    bf16x8 alo0 = *(const bf16x8*)(qs_lo + qoff);
    bf16x8 alo1 = *(const bf16x8*)(qs_lo + qoff + 32);

    // scores: S[64q x 256s], wave w owns q rows w*16..w*16+15
    f32x4 accS[16];
#pragma unroll
    for (int sf = 0; sf < 16; ++sf) accS[sf] = (f32x4)0.f;

    const size_t kbase =
        (size_t)(b * 2048 + n * 256 + l15) * 1024 + h * 64 + l4 * 8;
#pragma unroll
    for (int sf = 0; sf < 16; ++sf) {
      const size_t ko = kbase + (size_t)sf * 16 * 1024;
      bf16x8 bh0 = *(const bf16x8*)(kp_hi + ko);
      bf16x8 bh1 = *(const bf16x8*)(kp_hi + ko + 32);
      bf16x8 bl0 = *(const bf16x8*)(kp_lo + ko);
      bf16x8 bl1 = *(const bf16x8*)(kp_lo + ko + 32);
      accS[sf] = MFMA16(ahi0, bh0, accS[sf]);
      accS[sf] = MFMA16(ahi0, bl0, accS[sf]);
      accS[sf] = MFMA16(alo0, bh0, accS[sf]);
      accS[sf] = MFMA16(ahi1, bh1, accS[sf]);
      accS[sf] = MFMA16(ahi1, bl1, accS[sf]);
      accS[sf] = MFMA16(alo1, bh1, accS[sf]);
    }

    // softmax (fp32); mask s>q, scale 1/8
    float inv[4];
#pragma unroll
    for (int r = 0; r < 4; ++r) {
      const int qg = q0 + w * 16 + l4 * 4 + r;
      float mx = -3.0e38f;
#pragma unroll
      for (int sf = 0; sf < 16; ++sf) {
        int s = sf * 16 + l15;
        float vv = accS[sf][r] * 0.125f;
        if (s > qg) vv = -3.0e38f;
        accS[sf][r] = vv;
        mx = fmaxf(mx, vv);
      }
      mx = fmaxf(mx, __shfl_xor(mx, 1));
      mx = fmaxf(mx, __shfl_xor(mx, 2));
      mx = fmaxf(mx, __shfl_xor(mx, 4));
      mx = fmaxf(mx, __shfl_xor(mx, 8));
      float sum = 0.f;
#pragma unroll
      for (int sf = 0; sf < 16; ++sf) {
        float e = __expf(accS[sf][r] - mx);
        accS[sf][r] = e;
        sum += e;
      }
      sum += __shfl_xor(sum, 1);
      sum += __shfl_xor(sum, 2);
      sum += __shfl_xor(sum, 4);
      sum += __shfl_xor(sum, 8);
      inv[r] = 1.0f / sum;
    }

    __syncthreads();  // all P_lds readers of previous head done
#pragma unroll
    for (int r = 0; r < 4; ++r)
#pragma unroll
      for (int sf = 0; sf < 16; ++sf)
        P_lds[w * 16 + l4 * 4 + r][sf * 16 + l15] = f2bf(accS[sf][r] * inv[r]);
    __syncthreads();

    // attn_out: one full row (1 KB) per wave per pass, non-temporal
    const size_t abase =
        (((size_t)b * LTOT + (size_t)n * LQ + q0) * H_ + h) * SEGW;
#pragma unroll
    for (int pass = 0; pass < 16; ++pass) {
      int row = pass * 4 + w;
      us4 p4 = *(const us4*)&P_lds[row][lane * 4];
      f32x4 f;
      f[0] = bf2f(p4.x); f[1] = bf2f(p4.y);
      f[2] = bf2f(p4.z); f[3] = bf2f(p4.w);
      __builtin_nontemporal_store(
          f, (f32x4*)(attn_out + abase + (size_t)row * (H_ * SEGW) + lane * 4));
    }

    // PV: accO += P(64x256) @ V^T fragments (direct global B-operand)
#pragma unroll
    for (int kc = 0; kc < 8; ++kc) {
      bf16x8 pa = *(const bf16x8*)&P_lds[w * 16 + l15][kc * 32 + l4 * 8];
#pragma unroll
      for (int vf = 0; vf < 4; ++vf) {
        bf16x8 b8 = *(const bf16x8*)(vbase + (size_t)(vf * 16 + l15) * 256 +
                                     kc * 32 + l4 * 8);
        accO[vf] = MFMA16(pa, b8, accO[vf]);
      }
    }
  }

  // partial head-sum (4 heads) / 16 -> bf16
  const float s16 = 1.0f / 16.0f;
#pragma unroll
  for (int vf = 0; vf < 4; ++vf)
#pragma unroll
    for (int r = 0; r < 4; ++r)
      mhp[((size_t)hg * 16384 + (size_t)pair * 1024 + q0 + w * 16 + l4 * 4 + r) *
              64 + vf * 16 + l15] = f2bf(accO[vf][r] * s16);
}

// ---------------- final: outputs = (sum_hg mhp)[16384,64] @ Wh[64,1024] ----
__global__ __launch_bounds__(256) void final_mfma_kernel(
    const unsigned short* __restrict__ mhp, const unsigned short* __restrict__ WhT_hi,
    float* __restrict__ outputs) {
  __shared__ unsigned short Af[64][72], Bf[128][72];
  const int m0 = blockIdx.x * 64, c0 = blockIdx.y * 128;
  const int tid = threadIdx.x, lane = tid & 63, w = tid >> 6;
  const int l15 = lane & 15, l4 = lane >> 4;
  {
    int f4 = tid & 15, row0 = tid >> 4;
#pragma unroll
    for (int p = 0; p < 4; ++p) {
      int r = row0 + p * 16;
      size_t m = (size_t)(m0 + r);
      float s0 = 0.f, s1 = 0.f, s2 = 0.f, s3 = 0.f;
#pragma unroll
      for (int hg = 0; hg < 4; ++hg) {
        us4 h4 = *(const us4*)(mhp + ((size_t)hg * 16384 + m) * 64 + f4 * 4);
        s0 += bf2f(h4.x); s1 += bf2f(h4.y); s2 += bf2f(h4.z); s3 += bf2f(h4.w);
      }
      us4 o;
      o.x = f2bf(s0); o.y = f2bf(s1); o.z = f2bf(s2); o.w = f2bf(s3);
      *(us4*)&Af[r][f4 * 4] = o;
    }
    int u = tid & 7, cb = tid >> 3;
#pragma unroll
    for (int p = 0; p < 4; ++p) {
      int c = cb + p * 32;
      *(bf16x8*)&Bf[c][u * 8] =
          *(const bf16x8*)(WhT_hi + (size_t)(c0 + c) * 64 + u * 8);
    }
  }
  __syncthreads();

  f32x4 acc[8];
#pragma unroll
  for (int cf = 0; cf < 8; ++cf) acc[cf] = (f32x4)0.f;
#pragma unroll
  for (int kc = 0; kc < 2; ++kc) {
    bf16x8 a8 = *(const bf16x8*)&Af[w * 16 + l15][kc * 32 + l4 * 8];
#pragma unroll
    for (int cf = 0; cf < 8; ++cf) {
      bf16x8 b8 = *(const bf16x8*)&Bf[cf * 16 + l15][kc * 32 + l4 * 8];
      acc[cf] = MFMA16(a8, b8, acc[cf]);
    }
  }
#pragma unroll
  for (int cf = 0; cf < 8; ++cf)
#pragma unroll
    for (int r = 0; r < 4; ++r)
      __builtin_nontemporal_store(
          acc[cf][r],
          outputs + (size_t)(m0 + w * 16 + l4 * 4 + r) * 1024 + c0 + cf * 16 + l15);
}

// ---------------------------------------------------------------------------
extern "C" void kernel_launch(void* const* d_in, const int* in_sizes, int n_in,
                              void* d_out, int out_size, void* d_ws,
                              size_t ws_size, hipStream_t stream) {
  const float* q  = (const float*)d_in[0];
  const float* k  = (const float*)d_in[1];
  const float* v  = (const float*)d_in[2];
  const float* Wq = (const float*)d_in[3];
  const float* bq = (const float*)d_in[4];
  const float* Wk = (const float*)d_in[5];
  const float* bk = (const float*)d_in[6];
  const float* Wv = (const float*)d_in[7];
  const float* bv = (const float*)d_in[8];
  const float* Wh = (const float*)d_in[9];

  float* outputs  = (float*)d_out;
  float* attn_out = (float*)d_out + (size_t)B_ * LTOT * D_;

  char* ws = (char*)d_ws;
  // layout (bytes); mhp (8MB, 4 bf16 partials) overlays WqT/WkT (dead after proj)
  unsigned short* WqT_hi = (unsigned short*)(ws + 0);            // 2MB
  unsigned short* WqT_lo = (unsigned short*)(ws + (2u << 20));   // 2MB
  unsigned short* WkT_hi = (unsigned short*)(ws + (4u << 20));   // 2MB
  unsigned short* WkT_lo = (unsigned short*)(ws + (6u << 20));   // 2MB
  unsigned short* mhp    = (unsigned short*)(ws + 0);            // 8MB overlay
  unsigned short* WvT_hi = (unsigned short*)(ws + (8u << 20));           // 128KB
  unsigned short* WvT_lo = (unsigned short*)(ws + (8u << 20) + 131072);  // 128KB
  unsigned short* WhT_hi = (unsigned short*)(ws + (8u << 20) + 262144);  // 128KB
  unsigned short* WhT_lo = (unsigned short*)(ws + (8u << 20) + 393216);  // 128KB
  unsigned short* qs_hi  = (unsigned short*)(ws + (8u << 20) + 524288);  // 4MB
  unsigned short* qs_lo  = (unsigned short*)((char*)qs_hi + (4u << 20));
  unsigned short* kp_hi  = (unsigned short*)((char*)qs_lo + (4u << 20));  // 8MB
  unsigned short* kp_lo  = (unsigned short*)((char*)kp_hi + (8u << 20));  // 8MB
  unsigned short* vpTg   = (unsigned short*)((char*)kp_lo + (8u << 20));  // 512KB

  transpose_split_kernel<<<dim3(32, 2, 16), 256, 0, stream>>>(Wq, WqT_hi, WqT_lo, 1024, 64);
  transpose_split_kernel<<<dim3(32, 2, 16), 256, 0, stream>>>(Wk, WkT_hi, WkT_lo, 1024, 64);
  transpose_split_kernel<<<dim3(32, 2, 1), 256, 0, stream>>>(Wv, WvT_hi, WvT_lo, 1024, 64);
  transpose_split_kernel<<<dim3(2, 32, 1), 256, 0, stream>>>(Wh, WhT_hi, WhT_lo, 64, 1024);

  proj_split_kernel<<<dim3(16, 8), 256, 0, stream>>>(q, WqT_hi, WqT_lo, bq, qs_hi, qs_lo);
  proj_split_kernel<<<dim3(32, 8), 256, 0, stream>>>(k, WkT_hi, WkT_lo, bk, kp_hi, kp_lo);
  vproj_kernel<<<dim3(64), 256, 0, stream>>>(v, WvT_hi, bv, vpTg);

  fused_attn_kernel<<<dim3(1024), 256, 0, stream>>>(qs_hi, qs_lo, kp_hi, kp_lo,
                                                    vpTg, attn_out, mhp);
  final_mfma_kernel<<<dim3(256, 8), 256, 0, stream>>>(mhp, WhT_hi, outputs);
}

// Round 4
// 205.571 us; speedup vs baseline: 3.2864x; 2.1215x over previous
//
#include <hip/hip_runtime.h>

// ---------------------------------------------------------------------------
// Round 4: fp16 pipeline; fused attn with async K staging (global_load_lds,
// XOR-swizzled, double-buffered), V in VGPRs, P overlay, coalesced NT writes.
// B=2 Lq=1024 Lkv=2048 D=1024 H=16 dk=dv=64 SEG=256 nseg=8 L=8192
// d_out = [outputs (2*8192*1024) f32] ++ [attn_out (2*8192*16*256) f32]
// ---------------------------------------------------------------------------

#define B_ 2
#define LQ 1024
#define LKV 2048
#define D_ 1024
#define H_ 16
#define DK 64
#define SEGW 256
#define NSEG 8
#define LTOT 8192

typedef _Float16 f16;
typedef __attribute__((ext_vector_type(8))) _Float16 f16x8;
typedef __attribute__((ext_vector_type(4))) _Float16 f16x4;
typedef __attribute__((ext_vector_type(4))) float f32x4;

#define MFMA_F16(a, b, c) __builtin_amdgcn_mfma_f32_16x16x32_f16((a), (b), (c), 0, 0, 0)

// ---------------- transpose W[h][D][N] -> WT[(h*N+n)][D] f16 ----------------
__global__ __launch_bounds__(256) void transpose_qk_kernel(
    const float* __restrict__ Wq, const float* __restrict__ Wk,
    f16* __restrict__ WqT, f16* __restrict__ WkT) {
  __shared__ float T[32][33];
  const int z = blockIdx.z;
  const float* sp = ((z < 16) ? Wq : Wk) + (size_t)(z & 15) * (D_ * DK);
  f16* dst = (z < 16) ? WqT : WkT;
  const int h = z & 15;
  const int d0 = blockIdx.x * 32, n0 = blockIdx.y * 32;
  const int c = threadIdx.x & 31, r0 = threadIdx.x >> 5;
#pragma unroll
  for (int i = 0; i < 4; ++i) {
    int r = r0 + i * 8;
    T[r][c] = sp[(size_t)(d0 + r) * DK + n0 + c];
  }
  __syncthreads();
#pragma unroll
  for (int i = 0; i < 4; ++i) {
    int rr = r0 + i * 8;
    dst[(size_t)(h * DK + n0 + rr) * D_ + d0 + c] = (f16)T[c][rr];
  }
}

__global__ __launch_bounds__(256) void transpose_f16_kernel(
    const float* __restrict__ src, f16* __restrict__ dst, int D, int N) {
  __shared__ float T[32][33];
  const int d0 = blockIdx.x * 32, n0 = blockIdx.y * 32;
  const int c = threadIdx.x & 31, r0 = threadIdx.x >> 5;
#pragma unroll
  for (int i = 0; i < 4; ++i) {
    int r = r0 + i * 8;
    T[r][c] = src[(size_t)(d0 + r) * N + n0 + c];
  }
  __syncthreads();
#pragma unroll
  for (int i = 0; i < 4; ++i) {
    int rr = r0 + i * 8;
    dst[(size_t)(n0 + rr) * D + d0 + c] = (f16)T[c][rr];
  }
}

// ---------------- proj: C = A[M,1024] @ W[1024, 1024(=16h*64)] + bias -------
// WT: [c][k] f16. Output head-major: C[((b*16 + c>>6)*Mb + mlocal)*64 + (c&63)]
__global__ __launch_bounds__(256) void proj_f16_kernel(
    const float* __restrict__ A, const f16* __restrict__ WT,
    const float* __restrict__ bias, f16* __restrict__ C, int Mb, int bshift) {
  __shared__ f16 Ah[128][40];
  __shared__ f16 Bh[128][40];
  const int m0 = blockIdx.x * 128, c0 = blockIdx.y * 128;
  const int tid = threadIdx.x, lane = tid & 63, w = tid >> 6;
  const int wr = w >> 1, wc = w & 1;
  const int l15 = lane & 15, l4 = lane >> 4;

  f32x4 acc[4][4];
#pragma unroll
  for (int i = 0; i < 4; ++i)
#pragma unroll
    for (int j = 0; j < 4; ++j) acc[i][j] = (f32x4)0.f;

  for (int k0 = 0; k0 < 1024; k0 += 32) {
    __syncthreads();
    {
      int f4 = tid & 7, row0 = tid >> 3;
#pragma unroll
      for (int p = 0; p < 4; ++p) {
        int r = row0 + p * 32;
        float4 a = *(const float4*)(A + (size_t)(m0 + r) * 1024 + k0 + f4 * 4);
        f16x4 h4;
        h4[0] = (f16)a.x; h4[1] = (f16)a.y; h4[2] = (f16)a.z; h4[3] = (f16)a.w;
        *(f16x4*)&Ah[r][f4 * 4] = h4;
      }
      int u = tid & 3, cb = tid >> 2;
#pragma unroll
      for (int p = 0; p < 2; ++p) {
        int cc = cb + p * 64;
        *(f16x8*)&Bh[cc][u * 8] =
            *(const f16x8*)(WT + (size_t)(c0 + cc) * 1024 + k0 + u * 8);
      }
    }
    __syncthreads();
    f16x8 ah[4], bh[4];
#pragma unroll
    for (int i = 0; i < 4; ++i) {
      ah[i] = *(const f16x8*)&Ah[wr * 64 + i * 16 + l15][l4 * 8];
      bh[i] = *(const f16x8*)&Bh[wc * 64 + i * 16 + l15][l4 * 8];
    }
#pragma unroll
    for (int i = 0; i < 4; ++i)
#pragma unroll
      for (int j = 0; j < 4; ++j) acc[i][j] = MFMA_F16(ah[i], bh[j], acc[i][j]);
  }

#pragma unroll
  for (int j = 0; j < 4; ++j) {
    int c = c0 + wc * 64 + j * 16 + l15;
    float bs = bias[c];
    int hidx = c >> 6, dk = c & 63;
#pragma unroll
    for (int i = 0; i < 4; ++i) {
#pragma unroll
      for (int r = 0; r < 4; ++r) {
        int m = m0 + wr * 64 + i * 16 + l4 * 4 + r;
        int b = m >> bshift;
        int ml = m - (b << bshift);
        C[((size_t)(b * 16 + hidx) * Mb + ml) * 64 + dk] = (f16)(acc[i][j][r] + bs);
      }
    }
  }
}

// ---------------- v-proj: vpTg[(pair*64 + dv)*256 + s] f16 ------------------
__global__ __launch_bounds__(256) void vproj_f16_kernel(
    const float* __restrict__ v, const f16* __restrict__ WvT,
    const float* __restrict__ bv, f16* __restrict__ vpTg) {
  __shared__ f16 Av[64][40], Bv[64][40];
  const int m0 = blockIdx.x * 64;
  const int tid = threadIdx.x, lane = tid & 63, w = tid >> 6;
  const int l15 = lane & 15, l4 = lane >> 4;

  f32x4 acc[4];
#pragma unroll
  for (int j = 0; j < 4; ++j) acc[j] = (f32x4)0.f;

  for (int k0 = 0; k0 < 1024; k0 += 32) {
    __syncthreads();
    {
      int f4 = tid & 7, row0 = tid >> 3;
#pragma unroll
      for (int p = 0; p < 2; ++p) {
        int r = row0 + p * 32;
        float4 a = *(const float4*)(v + (size_t)(m0 + r) * 1024 + k0 + f4 * 4);
        f16x4 h4;
        h4[0] = (f16)a.x; h4[1] = (f16)a.y; h4[2] = (f16)a.z; h4[3] = (f16)a.w;
        *(f16x4*)&Av[r][f4 * 4] = h4;
      }
      int u = tid & 3, cb = tid >> 2;
      *(f16x8*)&Bv[cb][u * 8] =
          *(const f16x8*)(WvT + (size_t)cb * 1024 + k0 + u * 8);
    }
    __syncthreads();
    f16x8 a8 = *(const f16x8*)&Av[w * 16 + l15][l4 * 8];
#pragma unroll
    for (int cf = 0; cf < 4; ++cf) {
      f16x8 b8 = *(const f16x8*)&Bv[cf * 16 + l15][l4 * 8];
      acc[cf] = MFMA_F16(a8, b8, acc[cf]);
    }
  }
#pragma unroll
  for (int cf = 0; cf < 4; ++cf) {
    int dv = cf * 16 + l15;
    float bvv = bv[dv];
#pragma unroll
    for (int r = 0; r < 4; ++r) {
      int m = m0 + w * 16 + l4 * 4 + r;
      int b = m >> 11, rest = m & 2047, n = rest >> 8, si = rest & 255;
      vpTg[((size_t)((b * 8 + n) * 64 + dv)) * 256 + si] = (f16)(acc[cf][r] + bvv);
    }
  }
}

// ---------------- fused attention -----------------------------------------
// grid 512: (pair 16) x (qt 16) x (head-half 2), XCD-swizzled.
// LDS: K double buffer 2x32KB (XOR-swizzled layout, staged via global_load_lds
// with inverse-swizzled source); P (fp16 [64][256], same swizzle) overlays the
// dead K buffer. V fragments held in VGPRs (wave = dv-quarter for PV).
__global__ __launch_bounds__(256, 2) void fused_attn_kernel(
    const f16* __restrict__ qs, const f16* __restrict__ kp,
    const f16* __restrict__ vpTg, float* __restrict__ attn_out,
    f16* __restrict__ mhp) {
  __shared__ __align__(16) char Kbuf[2][32768];

  const int bid = blockIdx.x;
  const int xcd = bid & 7, sub = bid >> 3;
  const int gg = xcd * 4 + (sub >> 4);  // 0..31
  const int qt = sub & 15;
  const int pair = gg & 15, hgIdx = gg >> 4;
  const int b = pair >> 3, n = pair & 7;
  const int q0 = qt * 64;

  const int tid = threadIdx.x, lane = tid & 63, w = tid >> 6;
  const int l15 = lane & 15, l4 = lane >> 4;

  // constant per-lane inverse-swizzled source offset (rule #21)
  const int laneoff =
      (lane >> 3) * 128 + (((lane & 7) * 16) ^ ((lane >> 3) << 4));

  // V fragments (wave's dv quarter), reused across all heads
  f16x8 vfrag[8];
  {
    const f16* vb = vpTg + ((size_t)(pair * 64 + w * 16 + l15)) * 256 + l4 * 8;
#pragma unroll
    for (int kc = 0; kc < 8; ++kc) vfrag[kc] = *(const f16x8*)(vb + kc * 32);
  }

#define STAGE_K(bufIdx, h)                                                      \
  {                                                                             \
    const char* src_ = (const char*)kp +                                        \
        ((size_t)((b * 16 + (h)) * 2048 + n * 256)) * 128;                      \
    char* lds_ = &Kbuf[bufIdx][0];                                              \
    _Pragma("unroll")                                                           \
    for (int j_ = 0; j_ < 8; ++j_) {                                            \
      int ch_ = w * 8 + j_;                                                     \
      __builtin_amdgcn_global_load_lds(                                         \
          (const __attribute__((address_space(1))) unsigned int*)(src_ +        \
              ch_ * 1024 + laneoff),                                            \
          (__attribute__((address_space(3))) unsigned int*)(lds_ + ch_ * 1024), \
          16, 0, 0);                                                            \
    }                                                                           \
  }

#define LOAD_Q(h, a0, a1)                                                       \
  {                                                                             \
    const f16* qp_ = qs +                                                       \
        ((size_t)((b * 16 + (h)) * 1024 + q0 + w * 16 + l15)) * 64 + l4 * 8;    \
    a0 = *(const f16x8*)qp_;                                                    \
    a1 = *(const f16x8*)(qp_ + 32);                                             \
  }

  f16x8 qa0, qa1, qn0, qn1;
  STAGE_K(0, hgIdx * 8);
  LOAD_Q(hgIdx * 8, qa0, qa1);
  qn0 = qa0; qn1 = qa1;

  f32x4 accO[4];
#pragma unroll
  for (int i = 0; i < 4; ++i) accO[i] = (f32x4)0.f;

  asm volatile("s_waitcnt vmcnt(0)" ::: "memory");
  __syncthreads();

#pragma unroll 1
  for (int hh = 0; hh < 8; ++hh) {
    const int h = hgIdx * 8 + hh;
    const int cur = hh & 1;
    if (hh < 7) {
      STAGE_K(cur ^ 1, h + 1);
      LOAD_Q(h + 1, qn0, qn1);
    }

    // ---- QK^T: wave w owns q rows w*16..w*16+15, all 256 s ----
    f32x4 accS[16];
#pragma unroll
    for (int sf = 0; sf < 16; ++sf) accS[sf] = (f32x4)0.f;
    const char* Kc = &Kbuf[cur][0];
    {
      const int sw = (l15 & 7) << 4;
#pragma unroll
      for (int sf = 0; sf < 16; ++sf) {
        const int rowb = (sf * 16 + l15) * 128;
        f16x8 b0 = *(const f16x8*)(Kc + rowb + ((l4 * 16) ^ sw));
        f16x8 b1 = *(const f16x8*)(Kc + rowb + ((64 + l4 * 16) ^ sw));
        accS[sf] = MFMA_F16(qa0, b0, accS[sf]);
        accS[sf] = MFMA_F16(qa1, b1, accS[sf]);
      }
    }

    // ---- softmax (f32), mask s>q, scale 1/8 ----
    float inv[4];
#pragma unroll
    for (int r = 0; r < 4; ++r) {
      const int qg = q0 + w * 16 + l4 * 4 + r;
      float mx = -3.0e38f;
#pragma unroll
      for (int sf = 0; sf < 16; ++sf) {
        int s = sf * 16 + l15;
        float vv = accS[sf][r] * 0.125f;
        if (s > qg) vv = -3.0e38f;
        accS[sf][r] = vv;
        mx = fmaxf(mx, vv);
      }
      mx = fmaxf(mx, __shfl_xor(mx, 1));
      mx = fmaxf(mx, __shfl_xor(mx, 2));
      mx = fmaxf(mx, __shfl_xor(mx, 4));
      mx = fmaxf(mx, __shfl_xor(mx, 8));
      float sum = 0.f;
#pragma unroll
      for (int sf = 0; sf < 16; ++sf) {
        float e = __expf(accS[sf][r] - mx);
        accS[sf][r] = e;
        sum += e;
      }
      sum += __shfl_xor(sum, 1);
      sum += __shfl_xor(sum, 2);
      sum += __shfl_xor(sum, 4);
      sum += __shfl_xor(sum, 8);
      inv[r] = 1.0f / sum;
    }

    __syncthreads();  // all K[cur] reads done -> safe to overlay P

    // ---- write P (f16, swizzled) into Kbuf[cur] ----
    char* Pc = &Kbuf[cur][0];
#pragma unroll
    for (int r = 0; r < 4; ++r) {
      const int q = w * 16 + l4 * 4 + r;
      const int sw = (q & 7) << 4;
      const int rowb = q * 512;
#pragma unroll
      for (int sf = 0; sf < 16; ++sf) {
        int s = sf * 16 + l15;
        *(f16*)(Pc + rowb + ((s * 2) ^ sw)) = (f16)(accS[sf][r] * inv[r]);
      }
    }
    __syncthreads();  // P visible to all waves

    // ---- attn_out: contiguous 1KB per wave-row, NT stores ----
    {
      const size_t base0 =
          (((size_t)b * LTOT + (size_t)n * LQ + q0) * H_ + h) * SEGW;
#pragma unroll
      for (int it = 0; it < 16; ++it) {
        const int q = w * 16 + it;
        f16x4 p4 =
            *(const f16x4*)(Pc + q * 512 + ((lane * 8) ^ ((q & 7) << 4)));
        f32x4 f;
        f[0] = (float)p4[0]; f[1] = (float)p4[1];
        f[2] = (float)p4[2]; f[3] = (float)p4[3];
        __builtin_nontemporal_store(
            f, (f32x4*)(attn_out + base0 + (size_t)q * (H_ * SEGW) + lane * 4));
      }
    }

    // ---- PV: wave w owns dv quarter; A = P rows (all 64 q) ----
#pragma unroll
    for (int kc = 0; kc < 8; ++kc) {
#pragma unroll
      for (int qb = 0; qb < 4; ++qb) {
        const int q = qb * 16 + l15;
        f16x8 pa = *(const f16x8*)(Pc + q * 512 +
                                   ((kc * 64 + l4 * 16) ^ ((q & 7) << 4)));
        accO[qb] = MFMA_F16(pa, vfrag[kc], accO[qb]);
      }
    }

    qa0 = qn0; qa1 = qn1;
    asm volatile("s_waitcnt vmcnt(0)" ::: "memory");
    __syncthreads();  // stage(h+1) landed; P reads done
  }

  // ---- epilogue: mhp[hgIdx][pair*1024 + q0 + q][dv] (f16 partial /16) ----
  {
    f16* mp = mhp + ((size_t)hgIdx * 16384 + (size_t)pair * 1024 + q0) * 64 +
              w * 16 + l15;
    const float s16 = 1.0f / 16.0f;
#pragma unroll
    for (int qb = 0; qb < 4; ++qb)
#pragma unroll
      for (int r = 0; r < 4; ++r)
        mp[(size_t)(qb * 16 + l4 * 4 + r) * 64] = (f16)(accO[qb][r] * s16);
  }
#undef STAGE_K
#undef LOAD_Q
}

// ---------------- final: outputs = (mhp0+mhp1)[16384,64] @ Wh[64,1024] -----
__global__ __launch_bounds__(256) void final_f16_kernel(
    const f16* __restrict__ mhp, const f16* __restrict__ WhT,
    float* __restrict__ outputs) {
  __shared__ f16 Af[64][72], Bf[128][72];
  const int m0 = blockIdx.x * 64, c0 = blockIdx.y * 128;
  const int tid = threadIdx.x, lane = tid & 63, w = tid >> 6;
  const int l15 = lane & 15, l4 = lane >> 4;
  {
    int u = tid & 7, row0 = tid >> 3;
#pragma unroll
    for (int p = 0; p < 2; ++p) {
      int r = row0 + p * 32;
      size_t mi = (size_t)(m0 + r) * 64 + u * 8;
      f16x8 a0 = *(const f16x8*)(mhp + mi);
      f16x8 a1 = *(const f16x8*)(mhp + (size_t)16384 * 64 + mi);
      *(f16x8*)&Af[r][u * 8] = a0 + a1;
    }
    int cb = tid >> 3;
#pragma unroll
    for (int p = 0; p < 4; ++p) {
      int c = cb + p * 32;
      *(f16x8*)&Bf[c][u * 8] = *(const f16x8*)(WhT + (size_t)(c0 + c) * 64 + u * 8);
    }
  }
  __syncthreads();

  f32x4 acc[8];
#pragma unroll
  for (int cf = 0; cf < 8; ++cf) acc[cf] = (f32x4)0.f;
#pragma unroll
  for (int kc = 0; kc < 2; ++kc) {
    f16x8 a8 = *(const f16x8*)&Af[w * 16 + l15][kc * 32 + l4 * 8];
#pragma unroll
    for (int cf = 0; cf < 8; ++cf) {
      f16x8 b8 = *(const f16x8*)&Bf[cf * 16 + l15][kc * 32 + l4 * 8];
      acc[cf] = MFMA_F16(a8, b8, acc[cf]);
    }
  }
#pragma unroll
  for (int cf = 0; cf < 8; ++cf)
#pragma unroll
    for (int r = 0; r < 4; ++r)
      __builtin_nontemporal_store(
          acc[cf][r], outputs + (size_t)(m0 + w * 16 + l4 * 4 + r) * 1024 + c0 +
                          cf * 16 + l15);
}

// ---------------------------------------------------------------------------
extern "C" void kernel_launch(void* const* d_in, const int* in_sizes, int n_in,
                              void* d_out, int out_size, void* d_ws,
                              size_t ws_size, hipStream_t stream) {
  const float* q  = (const float*)d_in[0];
  const float* k  = (const float*)d_in[1];
  const float* v  = (const float*)d_in[2];
  const float* Wq = (const float*)d_in[3];
  const float* bq = (const float*)d_in[4];
  const float* Wk = (const float*)d_in[5];
  const float* bk = (const float*)d_in[6];
  const float* Wv = (const float*)d_in[7];
  const float* bv = (const float*)d_in[8];
  const float* Wh = (const float*)d_in[9];

  float* outputs  = (float*)d_out;
  float* attn_out = (float*)d_out + (size_t)B_ * LTOT * D_;

  char* ws = (char*)d_ws;
  f16* WqT  = (f16*)(ws + 0);                       // 2MB
  f16* WkT  = (f16*)(ws + (2u << 20));              // 2MB
  f16* WvT  = (f16*)(ws + (4u << 20));              // 128KB
  f16* WhT  = (f16*)(ws + (4u << 20) + 131072);     // 128KB
  f16* qs   = (f16*)(ws + (4u << 20) + 262144);     // 4MB
  f16* kp   = (f16*)((char*)qs + (4u << 20));       // 8MB
  f16* vpTg = (f16*)((char*)kp + (8u << 20));       // 512KB
  f16* mhp  = (f16*)((char*)vpTg + (1u << 19));     // 4MB (2 partials)

  transpose_qk_kernel<<<dim3(32, 2, 32), 256, 0, stream>>>(Wq, Wk, WqT, WkT);
  transpose_f16_kernel<<<dim3(32, 2, 1), 256, 0, stream>>>(Wv, WvT, 1024, 64);
  transpose_f16_kernel<<<dim3(2, 32, 1), 256, 0, stream>>>(Wh, WhT, 64, 1024);

  proj_f16_kernel<<<dim3(16, 8), 256, 0, stream>>>(q, WqT, bq, qs, 1024, 10);
  proj_f16_kernel<<<dim3(32, 8), 256, 0, stream>>>(k, WkT, bk, kp, 2048, 11);
  vproj_f16_kernel<<<dim3(64), 256, 0, stream>>>(v, WvT, bv, vpTg);

  fused_attn_kernel<<<dim3(512), 256, 0, stream>>>(qs, kp, vpTg, attn_out, mhp);
  final_f16_kernel<<<dim3(256, 8), 256, 0, stream>>>(mhp, WhT, outputs);
}

// Round 5
// 131.116 us; speedup vs baseline: 5.1526x; 1.5678x over previous
//
#include <hip/hip_runtime.h>

// ---------------------------------------------------------------------------
// Round 5: counted-vmcnt + raw-barrier fused attention (no per-head store
// drain); consolidated prep (1 kernel) and projections (1 kernel).
// B=2 Lq=1024 Lkv=2048 D=1024 H=16 dk=dv=64 SEG=256 nseg=8 L=8192
// d_out = [outputs (2*8192*1024) f32] ++ [attn_out (2*8192*16*256) f32]
// ---------------------------------------------------------------------------

#define B_ 2
#define LQ 1024
#define LKV 2048
#define D_ 1024
#define H_ 16
#define DK 64
#define SEGW 256
#define NSEG 8
#define LTOT 8192

typedef _Float16 f16;
typedef __attribute__((ext_vector_type(8))) _Float16 f16x8;
typedef __attribute__((ext_vector_type(4))) _Float16 f16x4;
typedef __attribute__((ext_vector_type(4))) float f32x4;

#define MFMA_F16(a, b, c) __builtin_amdgcn_mfma_f32_16x16x32_f16((a), (b), (c), 0, 0, 0)

// ---------------- prep: all W transposes in one launch ----------------------
// bid 0..2047   : Wq/Wk [h][1024][64] -> WT[(h*64+n)][1024]
// bid 2048..2111: Wv    [1024][64]    -> WvT[n][1024]
// bid 2112..2175: Wh    [64][1024]    -> WhT[n][64]
__global__ __launch_bounds__(256) void prep_kernel(
    const float* __restrict__ Wq, const float* __restrict__ Wk,
    const float* __restrict__ Wv, const float* __restrict__ Wh,
    f16* __restrict__ WqT, f16* __restrict__ WkT, f16* __restrict__ WvT,
    f16* __restrict__ WhT) {
  __shared__ float T[32][33];
  const int bid = blockIdx.x;
  const float* src;
  f16* dst;
  int D, N, d0, n0;
  size_t soff = 0, doff = 0;
  if (bid < 2048) {
    int z = bid >> 6, inner = bid & 63;
    int h = z & 15;
    src = (z < 16) ? Wq : Wk;
    dst = (z < 16) ? WqT : WkT;
    soff = (size_t)h * (1024 * 64);
    doff = (size_t)h * (64 * 1024);
    D = 1024; N = 64;
    d0 = (inner & 31) * 32;
    n0 = (inner >> 5) * 32;
  } else if (bid < 2112) {
    int i = bid - 2048;
    src = Wv; dst = WvT; D = 1024; N = 64;
    d0 = (i & 31) * 32;
    n0 = (i >> 5) * 32;
  } else {
    int i = bid - 2112;
    src = Wh; dst = WhT; D = 64; N = 1024;
    d0 = (i & 1) * 32;
    n0 = (i >> 1) * 32;
  }
  const int c = threadIdx.x & 31, r0 = threadIdx.x >> 5;
#pragma unroll
  for (int i = 0; i < 4; ++i) {
    int r = r0 + i * 8;
    T[r][c] = src[soff + (size_t)(d0 + r) * N + n0 + c];
  }
  __syncthreads();
#pragma unroll
  for (int i = 0; i < 4; ++i) {
    int rr = r0 + i * 8;
    dst[doff + (size_t)(n0 + rr) * D + d0 + c] = (f16)T[c][rr];
  }
}

// ---------------- projection bodies ----------------------------------------
__device__ __forceinline__ void proj_body(
    const float* __restrict__ A, const f16* __restrict__ WT,
    const float* __restrict__ bias, f16* __restrict__ C, int Mb, int bshift,
    int m0, int c0, char* smem) {
  f16(*Ah)[40] = (f16(*)[40])smem;
  f16(*Bh)[40] = (f16(*)[40])(smem + 10240);
  const int tid = threadIdx.x, lane = tid & 63, w = tid >> 6;
  const int wr = w >> 1, wc = w & 1;
  const int l15 = lane & 15, l4 = lane >> 4;

  f32x4 acc[4][4];
#pragma unroll
  for (int i = 0; i < 4; ++i)
#pragma unroll
    for (int j = 0; j < 4; ++j) acc[i][j] = (f32x4)0.f;

  for (int k0 = 0; k0 < 1024; k0 += 32) {
    __syncthreads();
    {
      int f4 = tid & 7, row0 = tid >> 3;
#pragma unroll
      for (int p = 0; p < 4; ++p) {
        int r = row0 + p * 32;
        float4 a = *(const float4*)(A + (size_t)(m0 + r) * 1024 + k0 + f4 * 4);
        f16x4 h4;
        h4[0] = (f16)a.x; h4[1] = (f16)a.y; h4[2] = (f16)a.z; h4[3] = (f16)a.w;
        *(f16x4*)&Ah[r][f4 * 4] = h4;
      }
      int u = tid & 3, cb = tid >> 2;
#pragma unroll
      for (int p = 0; p < 2; ++p) {
        int cc = cb + p * 64;
        *(f16x8*)&Bh[cc][u * 8] =
            *(const f16x8*)(WT + (size_t)(c0 + cc) * 1024 + k0 + u * 8);
      }
    }
    __syncthreads();
    f16x8 ah[4], bh[4];
#pragma unroll
    for (int i = 0; i < 4; ++i) {
      ah[i] = *(const f16x8*)&Ah[wr * 64 + i * 16 + l15][l4 * 8];
      bh[i] = *(const f16x8*)&Bh[wc * 64 + i * 16 + l15][l4 * 8];
    }
#pragma unroll
    for (int i = 0; i < 4; ++i)
#pragma unroll
      for (int j = 0; j < 4; ++j) acc[i][j] = MFMA_F16(ah[i], bh[j], acc[i][j]);
  }

#pragma unroll
  for (int j = 0; j < 4; ++j) {
    int c = c0 + wc * 64 + j * 16 + l15;
    float bs = bias[c];
    int hidx = c >> 6, dk = c & 63;
#pragma unroll
    for (int i = 0; i < 4; ++i) {
#pragma unroll
      for (int r = 0; r < 4; ++r) {
        int m = m0 + wr * 64 + i * 16 + l4 * 4 + r;
        int b = m >> bshift;
        int ml = m - (b << bshift);
        C[((size_t)(b * 16 + hidx) * Mb + ml) * 64 + dk] = (f16)(acc[i][j][r] + bs);
      }
    }
  }
}

__device__ __forceinline__ void vproj_body(
    const float* __restrict__ v, const f16* __restrict__ WvT,
    const float* __restrict__ bv, f16* __restrict__ vpTg, int m0, char* smem) {
  f16(*Av)[40] = (f16(*)[40])smem;
  f16(*Bv)[40] = (f16(*)[40])(smem + 5120);
  const int tid = threadIdx.x, lane = tid & 63, w = tid >> 6;
  const int l15 = lane & 15, l4 = lane >> 4;

  f32x4 acc[4];
#pragma unroll
  for (int j = 0; j < 4; ++j) acc[j] = (f32x4)0.f;

  for (int k0 = 0; k0 < 1024; k0 += 32) {
    __syncthreads();
    {
      int f4 = tid & 7, row0 = tid >> 3;
#pragma unroll
      for (int p = 0; p < 2; ++p) {
        int r = row0 + p * 32;
        float4 a = *(const float4*)(v + (size_t)(m0 + r) * 1024 + k0 + f4 * 4);
        f16x4 h4;
        h4[0] = (f16)a.x; h4[1] = (f16)a.y; h4[2] = (f16)a.z; h4[3] = (f16)a.w;
        *(f16x4*)&Av[r][f4 * 4] = h4;
      }
      int u = tid & 3, cb = tid >> 2;
      *(f16x8*)&Bv[cb][u * 8] =
          *(const f16x8*)(WvT + (size_t)cb * 1024 + k0 + u * 8);
    }
    __syncthreads();
    f16x8 a8 = *(const f16x8*)&Av[w * 16 + l15][l4 * 8];
#pragma unroll
    for (int cf = 0; cf < 4; ++cf) {
      f16x8 b8 = *(const f16x8*)&Bv[cf * 16 + l15][l4 * 8];
      acc[cf] = MFMA_F16(a8, b8, acc[cf]);
    }
  }
#pragma unroll
  for (int cf = 0; cf < 4; ++cf) {
    int dv = cf * 16 + l15;
    float bvv = bv[dv];
#pragma unroll
    for (int r = 0; r < 4; ++r) {
      int m = m0 + w * 16 + l4 * 4 + r;
      int b = m >> 11, rest = m & 2047, n = rest >> 8, si = rest & 255;
      vpTg[((size_t)((b * 8 + n) * 64 + dv)) * 256 + si] = (f16)(acc[cf][r] + bvv);
    }
  }
}

// one launch for q-proj (128 blocks), k-proj (256), v-proj (64)
__global__ __launch_bounds__(256) void proj_all_kernel(
    const float* __restrict__ q, const float* __restrict__ k,
    const float* __restrict__ v, const f16* __restrict__ WqT,
    const f16* __restrict__ WkT, const f16* __restrict__ WvT,
    const float* __restrict__ bq, const float* __restrict__ bk,
    const float* __restrict__ bv, f16* __restrict__ qs, f16* __restrict__ kp,
    f16* __restrict__ vpTg) {
  __shared__ __align__(16) char smem[20480];
  const int bid = blockIdx.x;
  if (bid < 128) {
    proj_body(q, WqT, bq, qs, 1024, 10, (bid & 15) * 128, (bid >> 4) * 128, smem);
  } else if (bid < 384) {
    int i = bid - 128;
    proj_body(k, WkT, bk, kp, 2048, 11, (i & 31) * 128, (i >> 5) * 128, smem);
  } else {
    vproj_body(v, WvT, bv, vpTg, (bid - 384) * 64, smem);
  }
}

// ---------------- fused attention -----------------------------------------
// grid 512: (pair 16) x (qt 16) x (head-half 2), XCD-swizzled.
// Raw s_barrier + counted vmcnt: NT stores drain during the NEXT head's
// compute instead of stalling each head (T3/T4).
__global__ __launch_bounds__(256, 2) void fused_attn_kernel(
    const f16* __restrict__ qs, const f16* __restrict__ kp,
    const f16* __restrict__ vpTg, float* __restrict__ attn_out,
    f16* __restrict__ mhp) {
  __shared__ __align__(16) char Kbuf[2][32768];

  const int bid = blockIdx.x;
  const int xcd = bid & 7, sub = bid >> 3;
  const int gg = xcd * 4 + (sub >> 4);  // 0..31
  const int qt = sub & 15;
  const int pair = gg & 15, hgIdx = gg >> 4;
  const int b = pair >> 3, n = pair & 7;
  const int q0 = qt * 64;

  const int tid = threadIdx.x, lane = tid & 63, w = tid >> 6;
  const int l15 = lane & 15, l4 = lane >> 4;

  // per-lane inverse-swizzled source offset (rule #21: linear LDS dest,
  // pre-swizzled global source; reads apply the same XOR)
  const int laneoff =
      (lane >> 3) * 128 + (((lane & 7) * 16) ^ ((lane >> 3) << 4));

  // V fragments (wave's dv quarter), reused across all heads  [8 x b128 loads]
  f16x8 vfrag[8];
  {
    const f16* vb = vpTg + ((size_t)(pair * 64 + w * 16 + l15)) * 256 + l4 * 8;
#pragma unroll
    for (int kc = 0; kc < 8; ++kc) vfrag[kc] = *(const f16x8*)(vb + kc * 32);
  }

#define STAGE_K(bufIdx, h)                                                      \
  {                                                                             \
    const char* src_ = (const char*)kp +                                        \
        ((size_t)((b * 16 + (h)) * 2048 + n * 256)) * 128;                      \
    char* lds_ = &Kbuf[bufIdx][0];                                              \
    _Pragma("unroll")                                                           \
    for (int j_ = 0; j_ < 8; ++j_) {                                            \
      int ch_ = w * 8 + j_;                                                     \
      __builtin_amdgcn_global_load_lds(                                         \
          (const __attribute__((address_space(1))) unsigned int*)(src_ +        \
              ch_ * 1024 + laneoff),                                            \
          (__attribute__((address_space(3))) unsigned int*)(lds_ + ch_ * 1024), \
          16, 0, 0);                                                            \
    }                                                                           \
  }

#define LOAD_Q(h, a0, a1)                                                       \
  {                                                                             \
    const f16* qp_ = qs +                                                       \
        ((size_t)((b * 16 + (h)) * 1024 + q0 + w * 16 + l15)) * 64 + l4 * 8;    \
    a0 = *(const f16x8*)qp_;                                                    \
    a1 = *(const f16x8*)(qp_ + 32);                                             \
  }

  f16x8 qa0, qa1, qn0, qn1;
  STAGE_K(0, hgIdx * 8);            // 8 loads
  LOAD_Q(hgIdx * 8, qa0, qa1);      // 2 loads
  qn0 = qa0; qn1 = qa1;

  f32x4 accO[4];
#pragma unroll
  for (int i = 0; i < 4; ++i) accO[i] = (f32x4)0.f;

  // outstanding: vfrag(8) + stage(8) + Q(2); vmcnt(2) => vfrag+stage retired
  asm volatile("s_waitcnt vmcnt(2)" ::: "memory");
  __builtin_amdgcn_s_barrier();

#pragma unroll 1
  for (int hh = 0; hh < 8; ++hh) {
    const int h = hgIdx * 8 + hh;
    const int cur = hh & 1;
    if (hh < 7) {
      STAGE_K(cur ^ 1, h + 1);      // 8 loads (oldest of this iteration)
      LOAD_Q(h + 1, qn0, qn1);      // 2 loads
    }

    // ---- QK^T: wave w owns q rows w*16..w*16+15, all 256 s ----
    f32x4 accS[16];
#pragma unroll
    for (int sf = 0; sf < 16; ++sf) accS[sf] = (f32x4)0.f;
    const char* Kc = &Kbuf[cur][0];
    {
      const int sw = (l15 & 7) << 4;
      __builtin_amdgcn_s_setprio(1);
#pragma unroll
      for (int sf = 0; sf < 16; ++sf) {
        const int rowb = (sf * 16 + l15) * 128;
        f16x8 b0 = *(const f16x8*)(Kc + rowb + ((l4 * 16) ^ sw));
        f16x8 b1 = *(const f16x8*)(Kc + rowb + ((64 + l4 * 16) ^ sw));
        accS[sf] = MFMA_F16(qa0, b0, accS[sf]);
        accS[sf] = MFMA_F16(qa1, b1, accS[sf]);
      }
      __builtin_amdgcn_s_setprio(0);
    }

    // ---- softmax (f32), mask s>q, scale 1/8 ----
    float inv[4];
#pragma unroll
    for (int r = 0; r < 4; ++r) {
      const int qg = q0 + w * 16 + l4 * 4 + r;
      float mx = -3.0e38f;
#pragma unroll
      for (int sf = 0; sf < 16; ++sf) {
        int s = sf * 16 + l15;
        float vv = accS[sf][r] * 0.125f;
        if (s > qg) vv = -3.0e38f;
        accS[sf][r] = vv;
        mx = fmaxf(mx, vv);
      }
      mx = fmaxf(mx, __shfl_xor(mx, 1));
      mx = fmaxf(mx, __shfl_xor(mx, 2));
      mx = fmaxf(mx, __shfl_xor(mx, 4));
      mx = fmaxf(mx, __shfl_xor(mx, 8));
      float sum = 0.f;
#pragma unroll
      for (int sf = 0; sf < 16; ++sf) {
        float e = __expf(accS[sf][r] - mx);
        accS[sf][r] = e;
        sum += e;
      }
      sum += __shfl_xor(sum, 1);
      sum += __shfl_xor(sum, 2);
      sum += __shfl_xor(sum, 4);
      sum += __shfl_xor(sum, 8);
      inv[r] = 1.0f / sum;
    }

    // all waves done reading K[cur] (QK data consumed) -> safe to overlay P
    asm volatile("s_waitcnt lgkmcnt(0)" ::: "memory");
    __builtin_amdgcn_s_barrier();

    // ---- write P (f16, swizzled) into Kbuf[cur] ----
    char* Pc = &Kbuf[cur][0];
#pragma unroll
    for (int r = 0; r < 4; ++r) {
      const int q = w * 16 + l4 * 4 + r;
      const int sw = (q & 7) << 4;
      const int rowb = q * 512;
#pragma unroll
      for (int sf = 0; sf < 16; ++sf) {
        int s = sf * 16 + l15;
        *(f16*)(Pc + rowb + ((s * 2) ^ sw)) = (f16)(accS[sf][r] * inv[r]);
      }
    }
    asm volatile("s_waitcnt lgkmcnt(0)" ::: "memory");
    __builtin_amdgcn_s_barrier();

    // ---- attn_out: contiguous 1KB per wave-row, NT stores (16 / lane) ----
    {
      const size_t base0 =
          (((size_t)b * LTOT + (size_t)n * LQ + q0) * H_ + h) * SEGW;
#pragma unroll
      for (int it = 0; it < 16; ++it) {
        const int q = w * 16 + it;
        f16x4 p4 =
            *(const f16x4*)(Pc + q * 512 + ((lane * 8) ^ ((q & 7) << 4)));
        f32x4 f;
        f[0] = (float)p4[0]; f[1] = (float)p4[1];
        f[2] = (float)p4[2]; f[3] = (float)p4[3];
        __builtin_nontemporal_store(
            f, (f32x4*)(attn_out + base0 + (size_t)q * (H_ * SEGW) + lane * 4));
      }
    }

    // ---- PV: wave w owns dv quarter; A = P rows (all 64 q) ----
    __builtin_amdgcn_s_setprio(1);
#pragma unroll
    for (int kc = 0; kc < 8; ++kc) {
#pragma unroll
      for (int qb = 0; qb < 4; ++qb) {
        const int q = qb * 16 + l15;
        f16x8 pa = *(const f16x8*)(Pc + q * 512 +
                                   ((kc * 64 + l4 * 16) ^ ((q & 7) << 4)));
        accO[qb] = MFMA_F16(pa, vfrag[kc], accO[qb]);
      }
    }
    __builtin_amdgcn_s_setprio(0);

    qa0 = qn0; qa1 = qn1;
    // own ds_reads (PV) done before next head's DMA overwrites this buffer;
    // vmcnt(16): <=16 outstanding = this head's NT stores only -> staging for
    // h+1 has landed, but stores keep draining during head h+1's compute.
    asm volatile("s_waitcnt lgkmcnt(0)" ::: "memory");
    asm volatile("s_waitcnt vmcnt(16)" ::: "memory");
    __builtin_amdgcn_s_barrier();
  }

  // ---- epilogue: mhp[hgIdx][pair*1024 + q0 + q][dv] (f16 partial /16) ----
  {
    f16* mp = mhp + ((size_t)hgIdx * 16384 + (size_t)pair * 1024 + q0) * 64 +
              w * 16 + l15;
    const float s16 = 1.0f / 16.0f;
#pragma unroll
    for (int qb = 0; qb < 4; ++qb)
#pragma unroll
      for (int r = 0; r < 4; ++r)
        mp[(size_t)(qb * 16 + l4 * 4 + r) * 64] = (f16)(accO[qb][r] * s16);
  }
#undef STAGE_K
#undef LOAD_Q
}

// ---------------- final: outputs = (mhp0+mhp1)[16384,64] @ Wh[64,1024] -----
__global__ __launch_bounds__(256) void final_f16_kernel(
    const f16* __restrict__ mhp, const f16* __restrict__ WhT,
    float* __restrict__ outputs) {
  __shared__ f16 Af[64][72], Bf[128][72];
  const int m0 = blockIdx.x * 64, c0 = blockIdx.y * 128;
  const int tid = threadIdx.x, lane = tid & 63, w = tid >> 6;
  const int l15 = lane & 15, l4 = lane >> 4;
  {
    int u = tid & 7, row0 = tid >> 3;
#pragma unroll
    for (int p = 0; p < 2; ++p) {
      int r = row0 + p * 32;
      size_t mi = (size_t)(m0 + r) * 64 + u * 8;
      f16x8 a0 = *(const f16x8*)(mhp + mi);
      f16x8 a1 = *(const f16x8*)(mhp + (size_t)16384 * 64 + mi);
      *(f16x8*)&Af[r][u * 8] = a0 + a1;
    }
    int cb = tid >> 3;
#pragma unroll
    for (int p = 0; p < 4; ++p) {
      int c = cb + p * 32;
      *(f16x8*)&Bf[c][u * 8] = *(const f16x8*)(WhT + (size_t)(c0 + c) * 64 + u * 8);
    }
  }
  __syncthreads();

  f32x4 acc[8];
#pragma unroll
  for (int cf = 0; cf < 8; ++cf) acc[cf] = (f32x4)0.f;
#pragma unroll
  for (int kc = 0; kc < 2; ++kc) {
    f16x8 a8 = *(const f16x8*)&Af[w * 16 + l15][kc * 32 + l4 * 8];
#pragma unroll
    for (int cf = 0; cf < 8; ++cf) {
      f16x8 b8 = *(const f16x8*)&Bf[cf * 16 + l15][kc * 32 + l4 * 8];
      acc[cf] = MFMA_F16(a8, b8, acc[cf]);
    }
  }
#pragma unroll
  for (int cf = 0; cf < 8; ++cf)
#pragma unroll
    for (int r = 0; r < 4; ++r)
      __builtin_nontemporal_store(
          acc[cf][r], outputs + (size_t)(m0 + w * 16 + l4 * 4 + r) * 1024 + c0 +
                          cf * 16 + l15);
}

// ---------------------------------------------------------------------------
extern "C" void kernel_launch(void* const* d_in, const int* in_sizes, int n_in,
                              void* d_out, int out_size, void* d_ws,
                              size_t ws_size, hipStream_t stream) {
  const float* q  = (const float*)d_in[0];
  const float* k  = (const float*)d_in[1];
  const float* v  = (const float*)d_in[2];
  const float* Wq = (const float*)d_in[3];
  const float* bq = (const float*)d_in[4];
  const float* Wk = (const float*)d_in[5];
  const float* bk = (const float*)d_in[6];
  const float* Wv = (const float*)d_in[7];
  const float* bv = (const float*)d_in[8];
  const float* Wh = (const float*)d_in[9];

  float* outputs  = (float*)d_out;
  float* attn_out = (float*)d_out + (size_t)B_ * LTOT * D_;

  char* ws = (char*)d_ws;
  f16* WqT  = (f16*)(ws + 0);                       // 2MB
  f16* WkT  = (f16*)(ws + (2u << 20));              // 2MB
  f16* WvT  = (f16*)(ws + (4u << 20));              // 128KB
  f16* WhT  = (f16*)(ws + (4u << 20) + 131072);     // 128KB
  f16* qs   = (f16*)(ws + (4u << 20) + 262144);     // 4MB
  f16* kp   = (f16*)((char*)qs + (4u << 20));       // 8MB
  f16* vpTg = (f16*)((char*)kp + (8u << 20));       // 512KB
  f16* mhp  = (f16*)((char*)vpTg + (1u << 19));     // 4MB (2 partials)

  prep_kernel<<<dim3(2176), 256, 0, stream>>>(Wq, Wk, Wv, Wh, WqT, WkT, WvT, WhT);
  proj_all_kernel<<<dim3(448), 256, 0, stream>>>(q, k, v, WqT, WkT, WvT, bq, bk,
                                                 bv, qs, kp, vpTg);
  fused_attn_kernel<<<dim3(512), 256, 0, stream>>>(qs, kp, vpTg, attn_out, mhp);
  final_f16_kernel<<<dim3(256, 8), 256, 0, stream>>>(mhp, WhT, outputs);
}

// Round 6
// 125.470 us; speedup vs baseline: 5.3845x; 1.0450x over previous
//
#include <hip/hip_runtime.h>

// ---------------------------------------------------------------------------
// Round 6: software-pipelined projections (reg-prefetch + LDS double-buffer,
// 1 barrier/K-step); fused attn: PV before attn_out stores. Rest as round 5.
// B=2 Lq=1024 Lkv=2048 D=1024 H=16 dk=dv=64 SEG=256 nseg=8 L=8192
// d_out = [outputs (2*8192*1024) f32] ++ [attn_out (2*8192*16*256) f32]
// ---------------------------------------------------------------------------

#define B_ 2
#define LQ 1024
#define LKV 2048
#define D_ 1024
#define H_ 16
#define DK 64
#define SEGW 256
#define NSEG 8
#define LTOT 8192

typedef _Float16 f16;
typedef __attribute__((ext_vector_type(8))) _Float16 f16x8;
typedef __attribute__((ext_vector_type(4))) _Float16 f16x4;
typedef __attribute__((ext_vector_type(4))) float f32x4;

#define MFMA_F16(a, b, c) __builtin_amdgcn_mfma_f32_16x16x32_f16((a), (b), (c), 0, 0, 0)

// ---------------- prep: all W transposes in one launch ----------------------
__global__ __launch_bounds__(256) void prep_kernel(
    const float* __restrict__ Wq, const float* __restrict__ Wk,
    const float* __restrict__ Wv, const float* __restrict__ Wh,
    f16* __restrict__ WqT, f16* __restrict__ WkT, f16* __restrict__ WvT,
    f16* __restrict__ WhT) {
  __shared__ float T[32][33];
  const int bid = blockIdx.x;
  const float* src;
  f16* dst;
  int D, N, d0, n0;
  size_t soff = 0, doff = 0;
  if (bid < 2048) {
    int z = bid >> 6, inner = bid & 63;
    int h = z & 15;
    src = (z < 16) ? Wq : Wk;
    dst = (z < 16) ? WqT : WkT;
    soff = (size_t)h * (1024 * 64);
    doff = (size_t)h * (64 * 1024);
    D = 1024; N = 64;
    d0 = (inner & 31) * 32;
    n0 = (inner >> 5) * 32;
  } else if (bid < 2112) {
    int i = bid - 2048;
    src = Wv; dst = WvT; D = 1024; N = 64;
    d0 = (i & 31) * 32;
    n0 = (i >> 5) * 32;
  } else {
    int i = bid - 2112;
    src = Wh; dst = WhT; D = 64; N = 1024;
    d0 = (i & 1) * 32;
    n0 = (i >> 1) * 32;
  }
  const int c = threadIdx.x & 31, r0 = threadIdx.x >> 5;
#pragma unroll
  for (int i = 0; i < 4; ++i) {
    int r = r0 + i * 8;
    T[r][c] = src[soff + (size_t)(d0 + r) * N + n0 + c];
  }
  __syncthreads();
#pragma unroll
  for (int i = 0; i < 4; ++i) {
    int rr = r0 + i * 8;
    dst[doff + (size_t)(n0 + rr) * D + d0 + c] = (f16)T[c][rr];
  }
}

// ---------------- projection bodies (pipelined) -----------------------------
// LDS layout: Ah[2*128][40] f16 (20KB) + Bh[2*128][40] f16 (20KB) = 40KB
__device__ __forceinline__ void proj_body(
    const float* __restrict__ A, const f16* __restrict__ WT,
    const float* __restrict__ bias, f16* __restrict__ C, int Mb, int bshift,
    int m0, int c0, char* smem) {
  f16(*Ah)[40] = (f16(*)[40])smem;
  f16(*Bh)[40] = (f16(*)[40])(smem + 20480);
  const int tid = threadIdx.x, lane = tid & 63, w = tid >> 6;
  const int wr = w >> 1, wc = w & 1;
  const int l15 = lane & 15, l4 = lane >> 4;
  const int f4 = tid & 7, row0 = tid >> 3;  // A loader: 4 rows, 16B each
  const int u = tid & 3, cb = tid >> 2;     // B loader: 2 rows, 16B each

  f32x4 acc[4][4];
#pragma unroll
  for (int i = 0; i < 4; ++i)
#pragma unroll
    for (int j = 0; j < 4; ++j) acc[i][j] = (f32x4)0.f;

  float4 aR[4];
  f16x8 bR[2];

#define PLOAD(k0)                                                              \
  {                                                                            \
    _Pragma("unroll") for (int p = 0; p < 4; ++p) aR[p] =                      \
        *(const float4*)(A + (size_t)(m0 + row0 + p * 32) * 1024 + (k0) +      \
                         f4 * 4);                                              \
    _Pragma("unroll") for (int p = 0; p < 2; ++p) bR[p] =                      \
        *(const f16x8*)(WT + (size_t)(c0 + cb + p * 64) * 1024 + (k0) +        \
                        u * 8);                                                \
  }
#define PSTORE(bi)                                                             \
  {                                                                            \
    _Pragma("unroll") for (int p = 0; p < 4; ++p) {                            \
      f16x4 h4;                                                                \
      h4[0] = (f16)aR[p].x; h4[1] = (f16)aR[p].y;                              \
      h4[2] = (f16)aR[p].z; h4[3] = (f16)aR[p].w;                              \
      *(f16x4*)&Ah[(bi)*128 + row0 + p * 32][f4 * 4] = h4;                     \
    }                                                                          \
    _Pragma("unroll") for (int p = 0; p < 2; ++p)                              \
        *(f16x8*)&Bh[(bi)*128 + cb + p * 64][u * 8] = bR[p];                   \
  }

  PLOAD(0);
  PSTORE(0);
  __syncthreads();

#pragma unroll 2
  for (int k = 0; k < 32; ++k) {
    if (k + 1 < 32) PLOAD((k + 1) * 32);  // in flight during compute
    const int cbuf = (k & 1) * 128;
    f16x8 ah[4], bh[4];
#pragma unroll
    for (int i = 0; i < 4; ++i) {
      ah[i] = *(const f16x8*)&Ah[cbuf + wr * 64 + i * 16 + l15][l4 * 8];
      bh[i] = *(const f16x8*)&Bh[cbuf + wc * 64 + i * 16 + l15][l4 * 8];
    }
#pragma unroll
    for (int i = 0; i < 4; ++i)
#pragma unroll
      for (int j = 0; j < 4; ++j) acc[i][j] = MFMA_F16(ah[i], bh[j], acc[i][j]);
    if (k + 1 < 32) PSTORE((k + 1) & 1);
    __syncthreads();
  }
#undef PLOAD
#undef PSTORE

#pragma unroll
  for (int j = 0; j < 4; ++j) {
    int c = c0 + wc * 64 + j * 16 + l15;
    float bs = bias[c];
    int hidx = c >> 6, dk = c & 63;
#pragma unroll
    for (int i = 0; i < 4; ++i) {
#pragma unroll
      for (int r = 0; r < 4; ++r) {
        int m = m0 + wr * 64 + i * 16 + l4 * 4 + r;
        int b = m >> bshift;
        int ml = m - (b << bshift);
        C[((size_t)(b * 16 + hidx) * Mb + ml) * 64 + dk] = (f16)(acc[i][j][r] + bs);
      }
    }
  }
}

// LDS: Av[2*64][40] (10KB) + Bv[2*64][40] (10KB)
__device__ __forceinline__ void vproj_body(
    const float* __restrict__ v, const f16* __restrict__ WvT,
    const float* __restrict__ bv, f16* __restrict__ vpTg, int m0, char* smem) {
  f16(*Av)[40] = (f16(*)[40])smem;
  f16(*Bv)[40] = (f16(*)[40])(smem + 10240);
  const int tid = threadIdx.x, lane = tid & 63, w = tid >> 6;
  const int l15 = lane & 15, l4 = lane >> 4;
  const int f4 = tid & 7, row0 = tid >> 3;  // A loader: 2 rows
  const int u = tid & 3, cb = tid >> 2;     // B loader: 1 row

  f32x4 acc[4];
#pragma unroll
  for (int j = 0; j < 4; ++j) acc[j] = (f32x4)0.f;

  float4 aR[2];
  f16x8 bR;

#define VLOAD(k0)                                                              \
  {                                                                            \
    _Pragma("unroll") for (int p = 0; p < 2; ++p) aR[p] =                      \
        *(const float4*)(v + (size_t)(m0 + row0 + p * 32) * 1024 + (k0) +      \
                         f4 * 4);                                              \
    bR = *(const f16x8*)(WvT + (size_t)cb * 1024 + (k0) + u * 8);              \
  }
#define VSTORE(bi)                                                             \
  {                                                                            \
    _Pragma("unroll") for (int p = 0; p < 2; ++p) {                            \
      f16x4 h4;                                                                \
      h4[0] = (f16)aR[p].x; h4[1] = (f16)aR[p].y;                              \
      h4[2] = (f16)aR[p].z; h4[3] = (f16)aR[p].w;                              \
      *(f16x4*)&Av[(bi)*64 + row0 + p * 32][f4 * 4] = h4;                      \
    }                                                                          \
    *(f16x8*)&Bv[(bi)*64 + cb][u * 8] = bR;                                    \
  }

  VLOAD(0);
  VSTORE(0);
  __syncthreads();

#pragma unroll 2
  for (int k = 0; k < 32; ++k) {
    if (k + 1 < 32) VLOAD((k + 1) * 32);
    const int cbuf = (k & 1) * 64;
    f16x8 a8 = *(const f16x8*)&Av[cbuf + w * 16 + l15][l4 * 8];
#pragma unroll
    for (int cf = 0; cf < 4; ++cf) {
      f16x8 b8 = *(const f16x8*)&Bv[cbuf + cf * 16 + l15][l4 * 8];
      acc[cf] = MFMA_F16(a8, b8, acc[cf]);
    }
    if (k + 1 < 32) VSTORE((k + 1) & 1);
    __syncthreads();
  }
#undef VLOAD
#undef VSTORE

#pragma unroll
  for (int cf = 0; cf < 4; ++cf) {
    int dv = cf * 16 + l15;
    float bvv = bv[dv];
#pragma unroll
    for (int r = 0; r < 4; ++r) {
      int m = m0 + w * 16 + l4 * 4 + r;
      int b = m >> 11, rest = m & 2047, n = rest >> 8, si = rest & 255;
      vpTg[((size_t)((b * 8 + n) * 64 + dv)) * 256 + si] = (f16)(acc[cf][r] + bvv);
    }
  }
}

// one launch for q-proj (128 blocks), k-proj (256), v-proj (64)
__global__ __launch_bounds__(256) void proj_all_kernel(
    const float* __restrict__ q, const float* __restrict__ k,
    const float* __restrict__ v, const f16* __restrict__ WqT,
    const f16* __restrict__ WkT, const f16* __restrict__ WvT,
    const float* __restrict__ bq, const float* __restrict__ bk,
    const float* __restrict__ bv, f16* __restrict__ qs, f16* __restrict__ kp,
    f16* __restrict__ vpTg) {
  __shared__ __align__(16) char smem[40960];
  const int bid = blockIdx.x;
  if (bid < 128) {
    proj_body(q, WqT, bq, qs, 1024, 10, (bid & 15) * 128, (bid >> 4) * 128, smem);
  } else if (bid < 384) {
    int i = bid - 128;
    proj_body(k, WkT, bk, kp, 2048, 11, (i & 31) * 128, (i >> 5) * 128, smem);
  } else {
    vproj_body(v, WvT, bv, vpTg, (bid - 384) * 64, smem);
  }
}

// ---------------- fused attention -----------------------------------------
// grid 512: (pair 16) x (qt 16) x (head-half 2), XCD-swizzled.
// Raw s_barrier + counted vmcnt: NT stores drain during the NEXT head's
// compute. PV issued before the attn_out store loop.
__global__ __launch_bounds__(256, 2) void fused_attn_kernel(
    const f16* __restrict__ qs, const f16* __restrict__ kp,
    const f16* __restrict__ vpTg, float* __restrict__ attn_out,
    f16* __restrict__ mhp) {
  __shared__ __align__(16) char Kbuf[2][32768];

  const int bid = blockIdx.x;
  const int xcd = bid & 7, sub = bid >> 3;
  const int gg = xcd * 4 + (sub >> 4);  // 0..31
  const int qt = sub & 15;
  const int pair = gg & 15, hgIdx = gg >> 4;
  const int b = pair >> 3, n = pair & 7;
  const int q0 = qt * 64;

  const int tid = threadIdx.x, lane = tid & 63, w = tid >> 6;
  const int l15 = lane & 15, l4 = lane >> 4;

  // per-lane inverse-swizzled source offset (rule #21)
  const int laneoff =
      (lane >> 3) * 128 + (((lane & 7) * 16) ^ ((lane >> 3) << 4));

  // V fragments (wave's dv quarter), reused across all heads  [8 x b128]
  f16x8 vfrag[8];
  {
    const f16* vb = vpTg + ((size_t)(pair * 64 + w * 16 + l15)) * 256 + l4 * 8;
#pragma unroll
    for (int kc = 0; kc < 8; ++kc) vfrag[kc] = *(const f16x8*)(vb + kc * 32);
  }

#define STAGE_K(bufIdx, h)                                                      \
  {                                                                             \
    const char* src_ = (const char*)kp +                                        \
        ((size_t)((b * 16 + (h)) * 2048 + n * 256)) * 128;                      \
    char* lds_ = &Kbuf[bufIdx][0];                                              \
    _Pragma("unroll")                                                           \
    for (int j_ = 0; j_ < 8; ++j_) {                                            \
      int ch_ = w * 8 + j_;                                                     \
      __builtin_amdgcn_global_load_lds(                                         \
          (const __attribute__((address_space(1))) unsigned int*)(src_ +        \
              ch_ * 1024 + laneoff),                                            \
          (__attribute__((address_space(3))) unsigned int*)(lds_ + ch_ * 1024), \
          16, 0, 0);                                                            \
    }                                                                           \
  }

#define LOAD_Q(h, a0, a1)                                                       \
  {                                                                             \
    const f16* qp_ = qs +                                                       \
        ((size_t)((b * 16 + (h)) * 1024 + q0 + w * 16 + l15)) * 64 + l4 * 8;    \
    a0 = *(const f16x8*)qp_;                                                    \
    a1 = *(const f16x8*)(qp_ + 32);                                             \
  }

  f16x8 qa0, qa1, qn0, qn1;
  STAGE_K(0, hgIdx * 8);            // 8 loads
  LOAD_Q(hgIdx * 8, qa0, qa1);      // 2 loads
  qn0 = qa0; qn1 = qa1;

  f32x4 accO[4];
#pragma unroll
  for (int i = 0; i < 4; ++i) accO[i] = (f32x4)0.f;

  // outstanding: vfrag(8) + stage(8) + Q(2); vmcnt(2) => vfrag+stage retired
  asm volatile("s_waitcnt vmcnt(2)" ::: "memory");
  __builtin_amdgcn_s_barrier();

#pragma unroll 1
  for (int hh = 0; hh < 8; ++hh) {
    const int h = hgIdx * 8 + hh;
    const int cur = hh & 1;
    if (hh < 7) {
      STAGE_K(cur ^ 1, h + 1);      // 8 loads (oldest of this iteration)
      LOAD_Q(h + 1, qn0, qn1);      // 2 loads
    }

    // ---- QK^T: wave w owns q rows w*16..w*16+15, all 256 s ----
    f32x4 accS[16];
#pragma unroll
    for (int sf = 0; sf < 16; ++sf) accS[sf] = (f32x4)0.f;
    const char* Kc = &Kbuf[cur][0];
    {
      const int sw = (l15 & 7) << 4;
      __builtin_amdgcn_s_setprio(1);
#pragma unroll
      for (int sf = 0; sf < 16; ++sf) {
        const int rowb = (sf * 16 + l15) * 128;
        f16x8 b0 = *(const f16x8*)(Kc + rowb + ((l4 * 16) ^ sw));
        f16x8 b1 = *(const f16x8*)(Kc + rowb + ((64 + l4 * 16) ^ sw));
        accS[sf] = MFMA_F16(qa0, b0, accS[sf]);
        accS[sf] = MFMA_F16(qa1, b1, accS[sf]);
      }
      __builtin_amdgcn_s_setprio(0);
    }

    // ---- softmax (f32), mask s>q, scale 1/8 ----
    float inv[4];
#pragma unroll
    for (int r = 0; r < 4; ++r) {
      const int qg = q0 + w * 16 + l4 * 4 + r;
      float mx = -3.0e38f;
#pragma unroll
      for (int sf = 0; sf < 16; ++sf) {
        int s = sf * 16 + l15;
        float vv = accS[sf][r] * 0.125f;
        if (s > qg) vv = -3.0e38f;
        accS[sf][r] = vv;
        mx = fmaxf(mx, vv);
      }
      mx = fmaxf(mx, __shfl_xor(mx, 1));
      mx = fmaxf(mx, __shfl_xor(mx, 2));
      mx = fmaxf(mx, __shfl_xor(mx, 4));
      mx = fmaxf(mx, __shfl_xor(mx, 8));
      float sum = 0.f;
#pragma unroll
      for (int sf = 0; sf < 16; ++sf) {
        float e = __expf(accS[sf][r] - mx);
        accS[sf][r] = e;
        sum += e;
      }
      sum += __shfl_xor(sum, 1);
      sum += __shfl_xor(sum, 2);
      sum += __shfl_xor(sum, 4);
      sum += __shfl_xor(sum, 8);
      inv[r] = 1.0f / sum;
    }

    // all waves done reading K[cur] -> safe to overlay P
    asm volatile("s_waitcnt lgkmcnt(0)" ::: "memory");
    __builtin_amdgcn_s_barrier();

    // ---- write P (f16, swizzled) into Kbuf[cur] ----
    char* Pc = &Kbuf[cur][0];
#pragma unroll
    for (int r = 0; r < 4; ++r) {
      const int q = w * 16 + l4 * 4 + r;
      const int sw = (q & 7) << 4;
      const int rowb = q * 512;
#pragma unroll
      for (int sf = 0; sf < 16; ++sf) {
        int s = sf * 16 + l15;
        *(f16*)(Pc + rowb + ((s * 2) ^ sw)) = (f16)(accS[sf][r] * inv[r]);
      }
    }
    asm volatile("s_waitcnt lgkmcnt(0)" ::: "memory");
    __builtin_amdgcn_s_barrier();

    // ---- PV first: MFMAs enter the pipe; stores will issue under them ----
    __builtin_amdgcn_s_setprio(1);
#pragma unroll
    for (int kc = 0; kc < 8; ++kc) {
#pragma unroll
      for (int qb = 0; qb < 4; ++qb) {
        const int q = qb * 16 + l15;
        f16x8 pa = *(const f16x8*)(Pc + q * 512 +
                                   ((kc * 64 + l4 * 16) ^ ((q & 7) << 4)));
        accO[qb] = MFMA_F16(pa, vfrag[kc], accO[qb]);
      }
    }
    __builtin_amdgcn_s_setprio(0);

    // ---- attn_out: contiguous 1KB per wave-row, NT stores (16 / lane) ----
    {
      const size_t base0 =
          (((size_t)b * LTOT + (size_t)n * LQ + q0) * H_ + h) * SEGW;
#pragma unroll
      for (int it = 0; it < 16; ++it) {
        const int q = w * 16 + it;
        f16x4 p4 =
            *(const f16x4*)(Pc + q * 512 + ((lane * 8) ^ ((q & 7) << 4)));
        f32x4 f;
        f[0] = (float)p4[0]; f[1] = (float)p4[1];
        f[2] = (float)p4[2]; f[3] = (float)p4[3];
        __builtin_nontemporal_store(
            f, (f32x4*)(attn_out + base0 + (size_t)q * (H_ * SEGW) + lane * 4));
      }
    }

    qa0 = qn0; qa1 = qn1;
    // own LDS reads done before next head's DMA overwrites this buffer;
    // vmcnt(16): outstanding = stage(8)+Q(2)+stores(16) -> drains stage+Q,
    // stores keep draining during head h+1's compute.
    asm volatile("s_waitcnt lgkmcnt(0)" ::: "memory");
    asm volatile("s_waitcnt vmcnt(16)" ::: "memory");
    __builtin_amdgcn_s_barrier();
  }

  // ---- epilogue: mhp[hgIdx][pair*1024 + q0 + q][dv] (f16 partial /16) ----
  {
    f16* mp = mhp + ((size_t)hgIdx * 16384 + (size_t)pair * 1024 + q0) * 64 +
              w * 16 + l15;
    const float s16 = 1.0f / 16.0f;
#pragma unroll
    for (int qb = 0; qb < 4; ++qb)
#pragma unroll
      for (int r = 0; r < 4; ++r)
        mp[(size_t)(qb * 16 + l4 * 4 + r) * 64] = (f16)(accO[qb][r] * s16);
  }
#undef STAGE_K
#undef LOAD_Q
}

// ---------------- final: outputs = (mhp0+mhp1)[16384,64] @ Wh[64,1024] -----
__global__ __launch_bounds__(256) void final_f16_kernel(
    const f16* __restrict__ mhp, const f16* __restrict__ WhT,
    float* __restrict__ outputs) {
  __shared__ f16 Af[64][72], Bf[128][72];
  const int m0 = blockIdx.x * 64, c0 = blockIdx.y * 128;
  const int tid = threadIdx.x, lane = tid & 63, w = tid >> 6;
  const int l15 = lane & 15, l4 = lane >> 4;
  {
    int u = tid & 7, row0 = tid >> 3;
#pragma unroll
    for (int p = 0; p < 2; ++p) {
      int r = row0 + p * 32;
      size_t mi = (size_t)(m0 + r) * 64 + u * 8;
      f16x8 a0 = *(const f16x8*)(mhp + mi);
      f16x8 a1 = *(const f16x8*)(mhp + (size_t)16384 * 64 + mi);
      *(f16x8*)&Af[r][u * 8] = a0 + a1;
    }
    int cb = tid >> 3;
#pragma unroll
    for (int p = 0; p < 4; ++p) {
      int c = cb + p * 32;
      *(f16x8*)&Bf[c][u * 8] = *(const f16x8*)(WhT + (size_t)(c0 + c) * 64 + u * 8);
    }
  }
  __syncthreads();

  f32x4 acc[8];
#pragma unroll
  for (int cf = 0; cf < 8; ++cf) acc[cf] = (f32x4)0.f;
#pragma unroll
  for (int kc = 0; kc < 2; ++kc) {
    f16x8 a8 = *(const f16x8*)&Af[w * 16 + l15][kc * 32 + l4 * 8];
#pragma unroll
    for (int cf = 0; cf < 8; ++cf) {
      f16x8 b8 = *(const f16x8*)&Bf[cf * 16 + l15][kc * 32 + l4 * 8];
      acc[cf] = MFMA_F16(a8, b8, acc[cf]);
    }
  }
#pragma unroll
  for (int cf = 0; cf < 8; ++cf)
#pragma unroll
    for (int r = 0; r < 4; ++r)
      __builtin_nontemporal_store(
          acc[cf][r], outputs + (size_t)(m0 + w * 16 + l4 * 4 + r) * 1024 + c0 +
                          cf * 16 + l15);
}

// ---------------------------------------------------------------------------
extern "C" void kernel_launch(void* const* d_in, const int* in_sizes, int n_in,
                              void* d_out, int out_size, void* d_ws,
                              size_t ws_size, hipStream_t stream) {
  const float* q  = (const float*)d_in[0];
  const float* k  = (const float*)d_in[1];
  const float* v  = (const float*)d_in[2];
  const float* Wq = (const float*)d_in[3];
  const float* bq = (const float*)d_in[4];
  const float* Wk = (const float*)d_in[5];
  const float* bk = (const float*)d_in[6];
  const float* Wv = (const float*)d_in[7];
  const float* bv = (const float*)d_in[8];
  const float* Wh = (const float*)d_in[9];

  float* outputs  = (float*)d_out;
  float* attn_out = (float*)d_out + (size_t)B_ * LTOT * D_;

  char* ws = (char*)d_ws;
  f16* WqT  = (f16*)(ws + 0);                       // 2MB
  f16* WkT  = (f16*)(ws + (2u << 20));              // 2MB
  f16* WvT  = (f16*)(ws + (4u << 20));              // 128KB
  f16* WhT  = (f16*)(ws + (4u << 20) + 131072);     // 128KB
  f16* qs   = (f16*)(ws + (4u << 20) + 262144);     // 4MB
  f16* kp   = (f16*)((char*)qs + (4u << 20));       // 8MB
  f16* vpTg = (f16*)((char*)kp + (8u << 20));       // 512KB
  f16* mhp  = (f16*)((char*)vpTg + (1u << 19));     // 4MB (2 partials)

  prep_kernel<<<dim3(2176), 256, 0, stream>>>(Wq, Wk, Wv, Wh, WqT, WkT, WvT, WhT);
  proj_all_kernel<<<dim3(448), 256, 0, stream>>>(q, k, v, WqT, WkT, WvT, bq, bk,
                                                 bv, qs, kp, vpTg);
  fused_attn_kernel<<<dim3(512), 256, 0, stream>>>(qs, kp, vpTg, attn_out, mhp);
  final_f16_kernel<<<dim3(256, 8), 256, 0, stream>>>(mhp, WhT, outputs);
}

// Round 7
// 118.165 us; speedup vs baseline: 5.7173x; 1.0618x over previous
//
#include <hip/hip_runtime.h>

// ---------------------------------------------------------------------------
// Round 7: coalesced epilogues via LDS repack (proj, vproj, final);
// uniform-branch causal mask skip for qt>=4. Rest as round 6.
// B=2 Lq=1024 Lkv=2048 D=1024 H=16 dk=dv=64 SEG=256 nseg=8 L=8192
// d_out = [outputs (2*8192*1024) f32] ++ [attn_out (2*8192*16*256) f32]
// ---------------------------------------------------------------------------

#define B_ 2
#define LQ 1024
#define LKV 2048
#define D_ 1024
#define H_ 16
#define DK 64
#define SEGW 256
#define NSEG 8
#define LTOT 8192

typedef _Float16 f16;
typedef __attribute__((ext_vector_type(8))) _Float16 f16x8;
typedef __attribute__((ext_vector_type(4))) _Float16 f16x4;
typedef __attribute__((ext_vector_type(4))) float f32x4;

#define MFMA_F16(a, b, c) __builtin_amdgcn_mfma_f32_16x16x32_f16((a), (b), (c), 0, 0, 0)

// ---------------- prep: all W transposes in one launch ----------------------
__global__ __launch_bounds__(256) void prep_kernel(
    const float* __restrict__ Wq, const float* __restrict__ Wk,
    const float* __restrict__ Wv, const float* __restrict__ Wh,
    f16* __restrict__ WqT, f16* __restrict__ WkT, f16* __restrict__ WvT,
    f16* __restrict__ WhT) {
  __shared__ float T[32][33];
  const int bid = blockIdx.x;
  const float* src;
  f16* dst;
  int D, N, d0, n0;
  size_t soff = 0, doff = 0;
  if (bid < 2048) {
    int z = bid >> 6, inner = bid & 63;
    int h = z & 15;
    src = (z < 16) ? Wq : Wk;
    dst = (z < 16) ? WqT : WkT;
    soff = (size_t)h * (1024 * 64);
    doff = (size_t)h * (64 * 1024);
    D = 1024; N = 64;
    d0 = (inner & 31) * 32;
    n0 = (inner >> 5) * 32;
  } else if (bid < 2112) {
    int i = bid - 2048;
    src = Wv; dst = WvT; D = 1024; N = 64;
    d0 = (i & 31) * 32;
    n0 = (i >> 5) * 32;
  } else {
    int i = bid - 2112;
    src = Wh; dst = WhT; D = 64; N = 1024;
    d0 = (i & 1) * 32;
    n0 = (i >> 1) * 32;
  }
  const int c = threadIdx.x & 31, r0 = threadIdx.x >> 5;
#pragma unroll
  for (int i = 0; i < 4; ++i) {
    int r = r0 + i * 8;
    T[r][c] = src[soff + (size_t)(d0 + r) * N + n0 + c];
  }
  __syncthreads();
#pragma unroll
  for (int i = 0; i < 4; ++i) {
    int rr = r0 + i * 8;
    dst[doff + (size_t)(n0 + rr) * D + d0 + c] = (f16)T[c][rr];
  }
}

// ---------------- projection bodies (pipelined, repacked epilogue) ----------
// LDS: Ah[2*128][40] (20KB) + Bh[2*128][40] (20KB); epilogue Cst[128][136]
__device__ __forceinline__ void proj_body(
    const float* __restrict__ A, const f16* __restrict__ WT,
    const float* __restrict__ bias, f16* __restrict__ C, int Mb, int bshift,
    int m0, int c0, char* smem) {
  f16(*Ah)[40] = (f16(*)[40])smem;
  f16(*Bh)[40] = (f16(*)[40])(smem + 20480);
  const int tid = threadIdx.x, lane = tid & 63, w = tid >> 6;
  const int wr = w >> 1, wc = w & 1;
  const int l15 = lane & 15, l4 = lane >> 4;
  const int f4 = tid & 7, row0 = tid >> 3;  // A loader: 4 rows, 16B each
  const int u = tid & 3, cb = tid >> 2;     // B loader: 2 rows, 16B each

  f32x4 acc[4][4];
#pragma unroll
  for (int i = 0; i < 4; ++i)
#pragma unroll
    for (int j = 0; j < 4; ++j) acc[i][j] = (f32x4)0.f;

  float4 aR[4];
  f16x8 bR[2];

#define PLOAD(k0)                                                              \
  {                                                                            \
    _Pragma("unroll") for (int p = 0; p < 4; ++p) aR[p] =                      \
        *(const float4*)(A + (size_t)(m0 + row0 + p * 32) * 1024 + (k0) +      \
                         f4 * 4);                                              \
    _Pragma("unroll") for (int p = 0; p < 2; ++p) bR[p] =                      \
        *(const f16x8*)(WT + (size_t)(c0 + cb + p * 64) * 1024 + (k0) +        \
                        u * 8);                                                \
  }
#define PSTORE(bi)                                                             \
  {                                                                            \
    _Pragma("unroll") for (int p = 0; p < 4; ++p) {                            \
      f16x4 h4;                                                                \
      h4[0] = (f16)aR[p].x; h4[1] = (f16)aR[p].y;                              \
      h4[2] = (f16)aR[p].z; h4[3] = (f16)aR[p].w;                              \
      *(f16x4*)&Ah[(bi)*128 + row0 + p * 32][f4 * 4] = h4;                     \
    }                                                                          \
    _Pragma("unroll") for (int p = 0; p < 2; ++p)                              \
        *(f16x8*)&Bh[(bi)*128 + cb + p * 64][u * 8] = bR[p];                   \
  }

  PLOAD(0);
  PSTORE(0);
  __syncthreads();

#pragma unroll 2
  for (int k = 0; k < 32; ++k) {
    if (k + 1 < 32) PLOAD((k + 1) * 32);  // in flight during compute
    const int cbuf = (k & 1) * 128;
    f16x8 ah[4], bh[4];
#pragma unroll
    for (int i = 0; i < 4; ++i) {
      ah[i] = *(const f16x8*)&Ah[cbuf + wr * 64 + i * 16 + l15][l4 * 8];
      bh[i] = *(const f16x8*)&Bh[cbuf + wc * 64 + i * 16 + l15][l4 * 8];
    }
#pragma unroll
    for (int i = 0; i < 4; ++i)
#pragma unroll
      for (int j = 0; j < 4; ++j) acc[i][j] = MFMA_F16(ah[i], bh[j], acc[i][j]);
    if (k + 1 < 32) PSTORE((k + 1) & 1);
    __syncthreads();
  }
#undef PLOAD
#undef PSTORE

  // ---- coalesced C store via LDS repack (Ah/Bh dead after last sync) ----
  f16(*Cst)[136] = (f16(*)[136])smem;  // 128x136 f16 = 34816 B
#pragma unroll
  for (int j = 0; j < 4; ++j) {
    int cl = wc * 64 + j * 16 + l15;
    float bs = bias[c0 + cl];
#pragma unroll
    for (int i = 0; i < 4; ++i)
#pragma unroll
      for (int r = 0; r < 4; ++r)
        Cst[wr * 64 + i * 16 + l4 * 4 + r][cl] = (f16)(acc[i][j][r] + bs);
  }
  __syncthreads();
#pragma unroll
  for (int p = 0; p < 8; ++p) {
    int row = p * 16 + (tid >> 4);
    int col = (tid & 15) * 8;
    f16x8 vv = *(const f16x8*)&Cst[row][col];
    int m = m0 + row, c = c0 + col;
    int bb = m >> bshift, ml = m - (bb << bshift);
    int hidx = c >> 6, dk = c & 63;
    *(f16x8*)(C + ((size_t)(bb * 16 + hidx) * Mb + ml) * 64 + dk) = vv;
  }
}

// LDS: Av[2*64][40] (10KB) + Bv[2*64][40] (10KB); epilogue Vst[64][72]
__device__ __forceinline__ void vproj_body(
    const float* __restrict__ v, const f16* __restrict__ WvT,
    const float* __restrict__ bv, f16* __restrict__ vpTg, int m0, char* smem) {
  f16(*Av)[40] = (f16(*)[40])smem;
  f16(*Bv)[40] = (f16(*)[40])(smem + 10240);
  const int tid = threadIdx.x, lane = tid & 63, w = tid >> 6;
  const int l15 = lane & 15, l4 = lane >> 4;
  const int f4 = tid & 7, row0 = tid >> 3;  // A loader: 2 rows
  const int u = tid & 3, cb = tid >> 2;     // B loader: 1 row

  f32x4 acc[4];
#pragma unroll
  for (int j = 0; j < 4; ++j) acc[j] = (f32x4)0.f;

  float4 aR[2];
  f16x8 bR;

#define VLOAD(k0)                                                              \
  {                                                                            \
    _Pragma("unroll") for (int p = 0; p < 2; ++p) aR[p] =                      \
        *(const float4*)(v + (size_t)(m0 + row0 + p * 32) * 1024 + (k0) +      \
                         f4 * 4);                                              \
    bR = *(const f16x8*)(WvT + (size_t)cb * 1024 + (k0) + u * 8);              \
  }
#define VSTORE(bi)                                                             \
  {                                                                            \
    _Pragma("unroll") for (int p = 0; p < 2; ++p) {                            \
      f16x4 h4;                                                                \
      h4[0] = (f16)aR[p].x; h4[1] = (f16)aR[p].y;                              \
      h4[2] = (f16)aR[p].z; h4[3] = (f16)aR[p].w;                              \
      *(f16x4*)&Av[(bi)*64 + row0 + p * 32][f4 * 4] = h4;                      \
    }                                                                          \
    *(f16x8*)&Bv[(bi)*64 + cb][u * 8] = bR;                                    \
  }

  VLOAD(0);
  VSTORE(0);
  __syncthreads();

#pragma unroll 2
  for (int k = 0; k < 32; ++k) {
    if (k + 1 < 32) VLOAD((k + 1) * 32);
    const int cbuf = (k & 1) * 64;
    f16x8 a8 = *(const f16x8*)&Av[cbuf + w * 16 + l15][l4 * 8];
#pragma unroll
    for (int cf = 0; cf < 4; ++cf) {
      f16x8 b8 = *(const f16x8*)&Bv[cbuf + cf * 16 + l15][l4 * 8];
      acc[cf] = MFMA_F16(a8, b8, acc[cf]);
    }
    if (k + 1 < 32) VSTORE((k + 1) & 1);
    __syncthreads();
  }
#undef VLOAD
#undef VSTORE

  // ---- coalesced vpTg store via LDS repack ----
  f16(*Vst)[72] = (f16(*)[72])smem;  // 64x72 f16 = 9216 B
#pragma unroll
  for (int cf = 0; cf < 4; ++cf) {
    float bvv = bv[cf * 16 + l15];
#pragma unroll
    for (int r = 0; r < 4; ++r)
      Vst[cf * 16 + l15][w * 16 + l4 * 4 + r] = (f16)(acc[cf][r] + bvv);
  }
  __syncthreads();
  const int b = m0 >> 11, rest = m0 & 2047, n = rest >> 8, si0 = rest & 255;
#pragma unroll
  for (int p = 0; p < 2; ++p) {
    int row = p * 32 + (tid >> 3);
    int col = (tid & 7) * 8;
    f16x8 vv = *(const f16x8*)&Vst[row][col];
    *(f16x8*)(vpTg + ((size_t)((b * 8 + n) * 64 + row)) * 256 + si0 + col) = vv;
  }
}

// one launch for q-proj (128 blocks), k-proj (256), v-proj (64)
__global__ __launch_bounds__(256) void proj_all_kernel(
    const float* __restrict__ q, const float* __restrict__ k,
    const float* __restrict__ v, const f16* __restrict__ WqT,
    const f16* __restrict__ WkT, const f16* __restrict__ WvT,
    const float* __restrict__ bq, const float* __restrict__ bk,
    const float* __restrict__ bv, f16* __restrict__ qs, f16* __restrict__ kp,
    f16* __restrict__ vpTg) {
  __shared__ __align__(16) char smem[40960];
  const int bid = blockIdx.x;
  if (bid < 128) {
    proj_body(q, WqT, bq, qs, 1024, 10, (bid & 15) * 128, (bid >> 4) * 128, smem);
  } else if (bid < 384) {
    int i = bid - 128;
    proj_body(k, WkT, bk, kp, 2048, 11, (i & 31) * 128, (i >> 5) * 128, smem);
  } else {
    vproj_body(v, WvT, bv, vpTg, (bid - 384) * 64, smem);
  }
}

// ---------------- fused attention -----------------------------------------
// grid 512: (pair 16) x (qt 16) x (head-half 2), XCD-swizzled.
__global__ __launch_bounds__(256, 2) void fused_attn_kernel(
    const f16* __restrict__ qs, const f16* __restrict__ kp,
    const f16* __restrict__ vpTg, float* __restrict__ attn_out,
    f16* __restrict__ mhp) {
  __shared__ __align__(16) char Kbuf[2][32768];

  const int bid = blockIdx.x;
  const int xcd = bid & 7, sub = bid >> 3;
  const int gg = xcd * 4 + (sub >> 4);  // 0..31
  const int qt = sub & 15;
  const int pair = gg & 15, hgIdx = gg >> 4;
  const int b = pair >> 3, n = pair & 7;
  const int q0 = qt * 64;

  const int tid = threadIdx.x, lane = tid & 63, w = tid >> 6;
  const int l15 = lane & 15, l4 = lane >> 4;

  // per-lane inverse-swizzled source offset (rule #21)
  const int laneoff =
      (lane >> 3) * 128 + (((lane & 7) * 16) ^ ((lane >> 3) << 4));

  // V fragments (wave's dv quarter), reused across all heads  [8 x b128]
  f16x8 vfrag[8];
  {
    const f16* vb = vpTg + ((size_t)(pair * 64 + w * 16 + l15)) * 256 + l4 * 8;
#pragma unroll
    for (int kc = 0; kc < 8; ++kc) vfrag[kc] = *(const f16x8*)(vb + kc * 32);
  }

#define STAGE_K(bufIdx, h)                                                      \
  {                                                                             \
    const char* src_ = (const char*)kp +                                        \
        ((size_t)((b * 16 + (h)) * 2048 + n * 256)) * 128;                      \
    char* lds_ = &Kbuf[bufIdx][0];                                              \
    _Pragma("unroll")                                                           \
    for (int j_ = 0; j_ < 8; ++j_) {                                            \
      int ch_ = w * 8 + j_;                                                     \
      __builtin_amdgcn_global_load_lds(                                         \
          (const __attribute__((address_space(1))) unsigned int*)(src_ +        \
              ch_ * 1024 + laneoff),                                            \
          (__attribute__((address_space(3))) unsigned int*)(lds_ + ch_ * 1024), \
          16, 0, 0);                                                            \
    }                                                                           \
  }

#define LOAD_Q(h, a0, a1)                                                       \
  {                                                                             \
    const f16* qp_ = qs +                                                       \
        ((size_t)((b * 16 + (h)) * 1024 + q0 + w * 16 + l15)) * 64 + l4 * 8;    \
    a0 = *(const f16x8*)qp_;                                                    \
    a1 = *(const f16x8*)(qp_ + 32);                                             \
  }

  f16x8 qa0, qa1, qn0, qn1;
  STAGE_K(0, hgIdx * 8);            // 8 loads
  LOAD_Q(hgIdx * 8, qa0, qa1);      // 2 loads
  qn0 = qa0; qn1 = qa1;

  f32x4 accO[4];
#pragma unroll
  for (int i = 0; i < 4; ++i) accO[i] = (f32x4)0.f;

  // outstanding: vfrag(8) + stage(8) + Q(2); vmcnt(2) => vfrag+stage retired
  asm volatile("s_waitcnt vmcnt(2)" ::: "memory");
  __builtin_amdgcn_s_barrier();

#pragma unroll 1
  for (int hh = 0; hh < 8; ++hh) {
    const int h = hgIdx * 8 + hh;
    const int cur = hh & 1;
    if (hh < 7) {
      STAGE_K(cur ^ 1, h + 1);      // 8 loads (oldest of this iteration)
      LOAD_Q(h + 1, qn0, qn1);      // 2 loads
    }

    // ---- QK^T: wave w owns q rows w*16..w*16+15, all 256 s ----
    f32x4 accS[16];
#pragma unroll
    for (int sf = 0; sf < 16; ++sf) accS[sf] = (f32x4)0.f;
    const char* Kc = &Kbuf[cur][0];
    {
      const int sw = (l15 & 7) << 4;
      __builtin_amdgcn_s_setprio(1);
#pragma unroll
      for (int sf = 0; sf < 16; ++sf) {
        const int rowb = (sf * 16 + l15) * 128;
        f16x8 b0 = *(const f16x8*)(Kc + rowb + ((l4 * 16) ^ sw));
        f16x8 b1 = *(const f16x8*)(Kc + rowb + ((64 + l4 * 16) ^ sw));
        accS[sf] = MFMA_F16(qa0, b0, accS[sf]);
        accS[sf] = MFMA_F16(qa1, b1, accS[sf]);
      }
      __builtin_amdgcn_s_setprio(0);
    }

    // ---- softmax (f32); mask only for q-tiles that intersect s>q ----
    float inv[4];
#pragma unroll
    for (int r = 0; r < 4; ++r) {
      const int qg = q0 + w * 16 + l4 * 4 + r;
      float mx = -3.0e38f;
      if (q0 < SEGW) {  // uniform per block: only qt<4 ever masks
#pragma unroll
        for (int sf = 0; sf < 16; ++sf) {
          int s = sf * 16 + l15;
          float vv = accS[sf][r] * 0.125f;
          if (s > qg) vv = -3.0e38f;
          accS[sf][r] = vv;
          mx = fmaxf(mx, vv);
        }
      } else {
#pragma unroll
        for (int sf = 0; sf < 16; ++sf) {
          float vv = accS[sf][r] * 0.125f;
          accS[sf][r] = vv;
          mx = fmaxf(mx, vv);
        }
      }
      mx = fmaxf(mx, __shfl_xor(mx, 1));
      mx = fmaxf(mx, __shfl_xor(mx, 2));
      mx = fmaxf(mx, __shfl_xor(mx, 4));
      mx = fmaxf(mx, __shfl_xor(mx, 8));
      float sum = 0.f;
#pragma unroll
      for (int sf = 0; sf < 16; ++sf) {
        float e = __expf(accS[sf][r] - mx);
        accS[sf][r] = e;
        sum += e;
      }
      sum += __shfl_xor(sum, 1);
      sum += __shfl_xor(sum, 2);
      sum += __shfl_xor(sum, 4);
      sum += __shfl_xor(sum, 8);
      inv[r] = 1.0f / sum;
    }

    // all waves done reading K[cur] -> safe to overlay P
    asm volatile("s_waitcnt lgkmcnt(0)" ::: "memory");
    __builtin_amdgcn_s_barrier();

    // ---- write P (f16, swizzled) into Kbuf[cur] ----
    char* Pc = &Kbuf[cur][0];
#pragma unroll
    for (int r = 0; r < 4; ++r) {
      const int q = w * 16 + l4 * 4 + r;
      const int sw = (q & 7) << 4;
      const int rowb = q * 512;
#pragma unroll
      for (int sf = 0; sf < 16; ++sf) {
        int s = sf * 16 + l15;
        *(f16*)(Pc + rowb + ((s * 2) ^ sw)) = (f16)(accS[sf][r] * inv[r]);
      }
    }
    asm volatile("s_waitcnt lgkmcnt(0)" ::: "memory");
    __builtin_amdgcn_s_barrier();

    // ---- PV first: MFMAs enter the pipe; stores will issue under them ----
    __builtin_amdgcn_s_setprio(1);
#pragma unroll
    for (int kc = 0; kc < 8; ++kc) {
#pragma unroll
      for (int qb = 0; qb < 4; ++qb) {
        const int q = qb * 16 + l15;
        f16x8 pa = *(const f16x8*)(Pc + q * 512 +
                                   ((kc * 64 + l4 * 16) ^ ((q & 7) << 4)));
        accO[qb] = MFMA_F16(pa, vfrag[kc], accO[qb]);
      }
    }
    __builtin_amdgcn_s_setprio(0);

    // ---- attn_out: contiguous 1KB per wave-row, NT stores (16 / lane) ----
    {
      const size_t base0 =
          (((size_t)b * LTOT + (size_t)n * LQ + q0) * H_ + h) * SEGW;
#pragma unroll
      for (int it = 0; it < 16; ++it) {
        const int q = w * 16 + it;
        f16x4 p4 =
            *(const f16x4*)(Pc + q * 512 + ((lane * 8) ^ ((q & 7) << 4)));
        f32x4 f;
        f[0] = (float)p4[0]; f[1] = (float)p4[1];
        f[2] = (float)p4[2]; f[3] = (float)p4[3];
        __builtin_nontemporal_store(
            f, (f32x4*)(attn_out + base0 + (size_t)q * (H_ * SEGW) + lane * 4));
      }
    }

    qa0 = qn0; qa1 = qn1;
    // vmcnt(16): drains stage+Q (and any older stores), leaves this head's
    // 16 NT stores draining under head h+1's compute.
    asm volatile("s_waitcnt lgkmcnt(0)" ::: "memory");
    asm volatile("s_waitcnt vmcnt(16)" ::: "memory");
    __builtin_amdgcn_s_barrier();
  }

  // ---- epilogue: mhp[hgIdx][pair*1024 + q0 + q][dv] (f16 partial /16) ----
  {
    f16* mp = mhp + ((size_t)hgIdx * 16384 + (size_t)pair * 1024 + q0) * 64 +
              w * 16 + l15;
    const float s16 = 1.0f / 16.0f;
#pragma unroll
    for (int qb = 0; qb < 4; ++qb)
#pragma unroll
      for (int r = 0; r < 4; ++r)
        mp[(size_t)(qb * 16 + l4 * 4 + r) * 64] = (f16)(accO[qb][r] * s16);
  }
#undef STAGE_K
#undef LOAD_Q
}

// ---------------- final: outputs = (mhp0+mhp1)[16384,64] @ Wh[64,1024] -----
__global__ __launch_bounds__(256) void final_f16_kernel(
    const f16* __restrict__ mhp, const f16* __restrict__ WhT,
    float* __restrict__ outputs) {
  __shared__ __align__(16) char smemF[33792];  // Af(9216)+Bf(18432) | Cst 64x132 f32
  f16(*Af)[72] = (f16(*)[72])smemF;
  f16(*Bf)[72] = (f16(*)[72])(smemF + 9216);
  const int m0 = blockIdx.x * 64, c0 = blockIdx.y * 128;
  const int tid = threadIdx.x, lane = tid & 63, w = tid >> 6;
  const int l15 = lane & 15, l4 = lane >> 4;
  {
    int u = tid & 7, row0 = tid >> 3;
#pragma unroll
    for (int p = 0; p < 2; ++p) {
      int r = row0 + p * 32;
      size_t mi = (size_t)(m0 + r) * 64 + u * 8;
      f16x8 a0 = *(const f16x8*)(mhp + mi);
      f16x8 a1 = *(const f16x8*)(mhp + (size_t)16384 * 64 + mi);
      *(f16x8*)&Af[r][u * 8] = a0 + a1;
    }
    int cb = tid >> 3;
#pragma unroll
    for (int p = 0; p < 4; ++p) {
      int c = cb + p * 32;
      *(f16x8*)&Bf[c][u * 8] = *(const f16x8*)(WhT + (size_t)(c0 + c) * 64 + u * 8);
    }
  }
  __syncthreads();

  f32x4 acc[8];
#pragma unroll
  for (int cf = 0; cf < 8; ++cf) acc[cf] = (f32x4)0.f;
#pragma unroll
  for (int kc = 0; kc < 2; ++kc) {
    f16x8 a8 = *(const f16x8*)&Af[w * 16 + l15][kc * 32 + l4 * 8];
#pragma unroll
    for (int cf = 0; cf < 8; ++cf) {
      f16x8 b8 = *(const f16x8*)&Bf[cf * 16 + l15][kc * 32 + l4 * 8];
      acc[cf] = MFMA_F16(a8, b8, acc[cf]);
    }
  }
  __syncthreads();  // Af/Bf reads done -> overlay staging

  // ---- coalesced outputs store via LDS repack ----
  float(*Cst)[132] = (float(*)[132])smemF;
#pragma unroll
  for (int cf = 0; cf < 8; ++cf)
#pragma unroll
    for (int r = 0; r < 4; ++r)
      Cst[w * 16 + l4 * 4 + r][cf * 16 + l15] = acc[cf][r];
  __syncthreads();
#pragma unroll
  for (int p = 0; p < 8; ++p) {
    int row = p * 8 + (tid >> 5);
    int col = (tid & 31) * 4;
    f32x4 vv = *(const f32x4*)&Cst[row][col];
    __builtin_nontemporal_store(
        vv, (f32x4*)(outputs + (size_t)(m0 + row) * 1024 + c0 + col));
  }
}

// ---------------------------------------------------------------------------
extern "C" void kernel_launch(void* const* d_in, const int* in_sizes, int n_in,
                              void* d_out, int out_size, void* d_ws,
                              size_t ws_size, hipStream_t stream) {
  const float* q  = (const float*)d_in[0];
  const float* k  = (const float*)d_in[1];
  const float* v  = (const float*)d_in[2];
  const float* Wq = (const float*)d_in[3];
  const float* bq = (const float*)d_in[4];
  const float* Wk = (const float*)d_in[5];
  const float* bk = (const float*)d_in[6];
  const float* Wv = (const float*)d_in[7];
  const float* bv = (const float*)d_in[8];
  const float* Wh = (const float*)d_in[9];

  float* outputs  = (float*)d_out;
  float* attn_out = (float*)d_out + (size_t)B_ * LTOT * D_;

  char* ws = (char*)d_ws;
  f16* WqT  = (f16*)(ws + 0);                       // 2MB
  f16* WkT  = (f16*)(ws + (2u << 20));              // 2MB
  f16* WvT  = (f16*)(ws + (4u << 20));              // 128KB
  f16* WhT  = (f16*)(ws + (4u << 20) + 131072);     // 128KB
  f16* qs   = (f16*)(ws + (4u << 20) + 262144);     // 4MB
  f16* kp   = (f16*)((char*)qs + (4u << 20));       // 8MB
  f16* vpTg = (f16*)((char*)kp + (8u << 20));       // 512KB
  f16* mhp  = (f16*)((char*)vpTg + (1u << 19));     // 4MB (2 partials)

  prep_kernel<<<dim3(2176), 256, 0, stream>>>(Wq, Wk, Wv, Wh, WqT, WkT, WvT, WhT);
  proj_all_kernel<<<dim3(448), 256, 0, stream>>>(q, k, v, WqT, WkT, WvT, bq, bk,
                                                 bv, qs, kp, vpTg);
  fused_attn_kernel<<<dim3(512), 256, 0, stream>>>(qs, kp, vpTg, attn_out, mhp);
  final_f16_kernel<<<dim3(256, 8), 256, 0, stream>>>(mhp, WhT, outputs);
}

// Round 8
// 115.061 us; speedup vs baseline: 5.8716x; 1.0270x over previous
//
#include <hip/hip_runtime.h>

// ---------------------------------------------------------------------------
// Round 8: swapped-operand QK^T (lane-local softmax rows, b64-packed P-write);
// prep consolidated to 544 blocks. Rest as round 7.
// B=2 Lq=1024 Lkv=2048 D=1024 H=16 dk=dv=64 SEG=256 nseg=8 L=8192
// d_out = [outputs (2*8192*1024) f32] ++ [attn_out (2*8192*16*256) f32]
// ---------------------------------------------------------------------------

#define B_ 2
#define LQ 1024
#define LKV 2048
#define D_ 1024
#define H_ 16
#define DK 64
#define SEGW 256
#define NSEG 8
#define LTOT 8192

typedef _Float16 f16;
typedef __attribute__((ext_vector_type(8))) _Float16 f16x8;
typedef __attribute__((ext_vector_type(4))) _Float16 f16x4;
typedef __attribute__((ext_vector_type(4))) float f32x4;

#define MFMA_F16(a, b, c) __builtin_amdgcn_mfma_f32_16x16x32_f16((a), (b), (c), 0, 0, 0)

// ---------------- prep: all W transposes, 4 tiles per block -----------------
__global__ __launch_bounds__(256) void prep_kernel(
    const float* __restrict__ Wq, const float* __restrict__ Wk,
    const float* __restrict__ Wv, const float* __restrict__ Wh,
    f16* __restrict__ WqT, f16* __restrict__ WkT, f16* __restrict__ WvT,
    f16* __restrict__ WhT) {
  __shared__ float T[32][33];
  const int c = threadIdx.x & 31, r0 = threadIdx.x >> 5;
#pragma unroll 1
  for (int t = 0; t < 4; ++t) {
    const int gidx = blockIdx.x * 4 + t;
    const float* src;
    f16* dst;
    int N, D2, d0, n0;
    size_t soff = 0, doff = 0;
    if (gidx < 2048) {
      int z = gidx >> 6, inner = gidx & 63;
      int h = z & 15;
      src = (z < 16) ? Wq : Wk;
      dst = (z < 16) ? WqT : WkT;
      soff = (size_t)h * (1024 * 64);
      doff = (size_t)h * (64 * 1024);
      N = 64; D2 = 1024;
      d0 = (inner & 31) * 32;
      n0 = (inner >> 5) * 32;
    } else if (gidx < 2112) {
      int i = gidx - 2048;
      src = Wv; dst = WvT; N = 64; D2 = 1024;
      d0 = (i & 31) * 32;
      n0 = (i >> 5) * 32;
    } else {
      int i = gidx - 2112;
      src = Wh; dst = WhT; N = 1024; D2 = 64;
      d0 = (i & 1) * 32;
      n0 = (i >> 1) * 32;
    }
#pragma unroll
    for (int i = 0; i < 4; ++i) {
      int r = r0 + i * 8;
      T[r][c] = src[soff + (size_t)(d0 + r) * N + n0 + c];
    }
    __syncthreads();
#pragma unroll
    for (int i = 0; i < 4; ++i) {
      int rr = r0 + i * 8;
      dst[doff + (size_t)(n0 + rr) * D2 + d0 + c] = (f16)T[c][rr];
    }
    __syncthreads();
  }
}

// ---------------- projection bodies (pipelined, repacked epilogue) ----------
__device__ __forceinline__ void proj_body(
    const float* __restrict__ A, const f16* __restrict__ WT,
    const float* __restrict__ bias, f16* __restrict__ C, int Mb, int bshift,
    int m0, int c0, char* smem) {
  f16(*Ah)[40] = (f16(*)[40])smem;
  f16(*Bh)[40] = (f16(*)[40])(smem + 20480);
  const int tid = threadIdx.x, lane = tid & 63, w = tid >> 6;
  const int wr = w >> 1, wc = w & 1;
  const int l15 = lane & 15, l4 = lane >> 4;
  const int f4 = tid & 7, row0 = tid >> 3;  // A loader: 4 rows, 16B each
  const int u = tid & 3, cb = tid >> 2;     // B loader: 2 rows, 16B each

  f32x4 acc[4][4];
#pragma unroll
  for (int i = 0; i < 4; ++i)
#pragma unroll
    for (int j = 0; j < 4; ++j) acc[i][j] = (f32x4)0.f;

  float4 aR[4];
  f16x8 bR[2];

#define PLOAD(k0)                                                              \
  {                                                                            \
    _Pragma("unroll") for (int p = 0; p < 4; ++p) aR[p] =                      \
        *(const float4*)(A + (size_t)(m0 + row0 + p * 32) * 1024 + (k0) +      \
                         f4 * 4);                                              \
    _Pragma("unroll") for (int p = 0; p < 2; ++p) bR[p] =                      \
        *(const f16x8*)(WT + (size_t)(c0 + cb + p * 64) * 1024 + (k0) +        \
                        u * 8);                                                \
  }
#define PSTORE(bi)                                                             \
  {                                                                            \
    _Pragma("unroll") for (int p = 0; p < 4; ++p) {                            \
      f16x4 h4;                                                                \
      h4[0] = (f16)aR[p].x; h4[1] = (f16)aR[p].y;                              \
      h4[2] = (f16)aR[p].z; h4[3] = (f16)aR[p].w;                              \
      *(f16x4*)&Ah[(bi)*128 + row0 + p * 32][f4 * 4] = h4;                     \
    }                                                                          \
    _Pragma("unroll") for (int p = 0; p < 2; ++p)                              \
        *(f16x8*)&Bh[(bi)*128 + cb + p * 64][u * 8] = bR[p];                   \
  }

  PLOAD(0);
  PSTORE(0);
  __syncthreads();

#pragma unroll 2
  for (int k = 0; k < 32; ++k) {
    if (k + 1 < 32) PLOAD((k + 1) * 32);  // in flight during compute
    const int cbuf = (k & 1) * 128;
    f16x8 ah[4], bh[4];
#pragma unroll
    for (int i = 0; i < 4; ++i) {
      ah[i] = *(const f16x8*)&Ah[cbuf + wr * 64 + i * 16 + l15][l4 * 8];
      bh[i] = *(const f16x8*)&Bh[cbuf + wc * 64 + i * 16 + l15][l4 * 8];
    }
#pragma unroll
    for (int i = 0; i < 4; ++i)
#pragma unroll
      for (int j = 0; j < 4; ++j) acc[i][j] = MFMA_F16(ah[i], bh[j], acc[i][j]);
    if (k + 1 < 32) PSTORE((k + 1) & 1);
    __syncthreads();
  }
#undef PLOAD
#undef PSTORE

  // ---- coalesced C store via LDS repack ----
  f16(*Cst)[136] = (f16(*)[136])smem;  // 128x136 f16 = 34816 B
#pragma unroll
  for (int j = 0; j < 4; ++j) {
    int cl = wc * 64 + j * 16 + l15;
    float bs = bias[c0 + cl];
#pragma unroll
    for (int i = 0; i < 4; ++i)
#pragma unroll
      for (int r = 0; r < 4; ++r)
        Cst[wr * 64 + i * 16 + l4 * 4 + r][cl] = (f16)(acc[i][j][r] + bs);
  }
  __syncthreads();
#pragma unroll
  for (int p = 0; p < 8; ++p) {
    int row = p * 16 + (tid >> 4);
    int col = (tid & 15) * 8;
    f16x8 vv = *(const f16x8*)&Cst[row][col];
    int m = m0 + row, c = c0 + col;
    int bb = m >> bshift, ml = m - (bb << bshift);
    int hidx = c >> 6, dk = c & 63;
    *(f16x8*)(C + ((size_t)(bb * 16 + hidx) * Mb + ml) * 64 + dk) = vv;
  }
}

__device__ __forceinline__ void vproj_body(
    const float* __restrict__ v, const f16* __restrict__ WvT,
    const float* __restrict__ bv, f16* __restrict__ vpTg, int m0, char* smem) {
  f16(*Av)[40] = (f16(*)[40])smem;
  f16(*Bv)[40] = (f16(*)[40])(smem + 10240);
  const int tid = threadIdx.x, lane = tid & 63, w = tid >> 6;
  const int l15 = lane & 15, l4 = lane >> 4;
  const int f4 = tid & 7, row0 = tid >> 3;  // A loader: 2 rows
  const int u = tid & 3, cb = tid >> 2;     // B loader: 1 row

  f32x4 acc[4];
#pragma unroll
  for (int j = 0; j < 4; ++j) acc[j] = (f32x4)0.f;

  float4 aR[2];
  f16x8 bR;

#define VLOAD(k0)                                                              \
  {                                                                            \
    _Pragma("unroll") for (int p = 0; p < 2; ++p) aR[p] =                      \
        *(const float4*)(v + (size_t)(m0 + row0 + p * 32) * 1024 + (k0) +      \
                         f4 * 4);                                              \
    bR = *(const f16x8*)(WvT + (size_t)cb * 1024 + (k0) + u * 8);              \
  }
#define VSTORE(bi)                                                             \
  {                                                                            \
    _Pragma("unroll") for (int p = 0; p < 2; ++p) {                            \
      f16x4 h4;                                                                \
      h4[0] = (f16)aR[p].x; h4[1] = (f16)aR[p].y;                              \
      h4[2] = (f16)aR[p].z; h4[3] = (f16)aR[p].w;                              \
      *(f16x4*)&Av[(bi)*64 + row0 + p * 32][f4 * 4] = h4;                      \
    }                                                                          \
    *(f16x8*)&Bv[(bi)*64 + cb][u * 8] = bR;                                    \
  }

  VLOAD(0);
  VSTORE(0);
  __syncthreads();

#pragma unroll 2
  for (int k = 0; k < 32; ++k) {
    if (k + 1 < 32) VLOAD((k + 1) * 32);
    const int cbuf = (k & 1) * 64;
    f16x8 a8 = *(const f16x8*)&Av[cbuf + w * 16 + l15][l4 * 8];
#pragma unroll
    for (int cf = 0; cf < 4; ++cf) {
      f16x8 b8 = *(const f16x8*)&Bv[cbuf + cf * 16 + l15][l4 * 8];
      acc[cf] = MFMA_F16(a8, b8, acc[cf]);
    }
    if (k + 1 < 32) VSTORE((k + 1) & 1);
    __syncthreads();
  }
#undef VLOAD
#undef VSTORE

  // ---- coalesced vpTg store via LDS repack ----
  f16(*Vst)[72] = (f16(*)[72])smem;  // 64x72 f16 = 9216 B
#pragma unroll
  for (int cf = 0; cf < 4; ++cf) {
    float bvv = bv[cf * 16 + l15];
#pragma unroll
    for (int r = 0; r < 4; ++r)
      Vst[cf * 16 + l15][w * 16 + l4 * 4 + r] = (f16)(acc[cf][r] + bvv);
  }
  __syncthreads();
  const int b = m0 >> 11, rest = m0 & 2047, n = rest >> 8, si0 = rest & 255;
#pragma unroll
  for (int p = 0; p < 2; ++p) {
    int row = p * 32 + (tid >> 3);
    int col = (tid & 7) * 8;
    f16x8 vv = *(const f16x8*)&Vst[row][col];
    *(f16x8*)(vpTg + ((size_t)((b * 8 + n) * 64 + row)) * 256 + si0 + col) = vv;
  }
}

__global__ __launch_bounds__(256) void proj_all_kernel(
    const float* __restrict__ q, const float* __restrict__ k,
    const float* __restrict__ v, const f16* __restrict__ WqT,
    const f16* __restrict__ WkT, const f16* __restrict__ WvT,
    const float* __restrict__ bq, const float* __restrict__ bk,
    const float* __restrict__ bv, f16* __restrict__ qs, f16* __restrict__ kp,
    f16* __restrict__ vpTg) {
  __shared__ __align__(16) char smem[40960];
  const int bid = blockIdx.x;
  if (bid < 128) {
    proj_body(q, WqT, bq, qs, 1024, 10, (bid & 15) * 128, (bid >> 4) * 128, smem);
  } else if (bid < 384) {
    int i = bid - 128;
    proj_body(k, WkT, bk, kp, 2048, 11, (i & 31) * 128, (i >> 5) * 128, smem);
  } else {
    vproj_body(v, WvT, bv, vpTg, (bid - 384) * 64, smem);
  }
}

// ---------------- fused attention -----------------------------------------
// grid 512: (pair 16) x (qt 16) x (head-half 2), XCD-swizzled.
// Swapped QK^T: accS = mfma(K,Q) -> lane owns ONE q (w*16+l15) and 64 s
// (sf*16 + l4*4 + r). Softmax: in-register + 2 shfl; P-write: 16 b64.
__global__ __launch_bounds__(256, 2) void fused_attn_kernel(
    const f16* __restrict__ qs, const f16* __restrict__ kp,
    const f16* __restrict__ vpTg, float* __restrict__ attn_out,
    f16* __restrict__ mhp) {
  __shared__ __align__(16) char Kbuf[2][32768];

  const int bid = blockIdx.x;
  const int xcd = bid & 7, sub = bid >> 3;
  const int gg = xcd * 4 + (sub >> 4);  // 0..31
  const int qt = sub & 15;
  const int pair = gg & 15, hgIdx = gg >> 4;
  const int b = pair >> 3, n = pair & 7;
  const int q0 = qt * 64;

  const int tid = threadIdx.x, lane = tid & 63, w = tid >> 6;
  const int l15 = lane & 15, l4 = lane >> 4;

  // per-lane inverse-swizzled source offset (rule #21)
  const int laneoff =
      (lane >> 3) * 128 + (((lane & 7) * 16) ^ ((lane >> 3) << 4));

  // V fragments (wave's dv quarter), reused across all heads  [8 x b128]
  f16x8 vfrag[8];
  {
    const f16* vb = vpTg + ((size_t)(pair * 64 + w * 16 + l15)) * 256 + l4 * 8;
#pragma unroll
    for (int kc = 0; kc < 8; ++kc) vfrag[kc] = *(const f16x8*)(vb + kc * 32);
  }

#define STAGE_K(bufIdx, h)                                                      \
  {                                                                             \
    const char* src_ = (const char*)kp +                                        \
        ((size_t)((b * 16 + (h)) * 2048 + n * 256)) * 128;                      \
    char* lds_ = &Kbuf[bufIdx][0];                                              \
    _Pragma("unroll")                                                           \
    for (int j_ = 0; j_ < 8; ++j_) {                                            \
      int ch_ = w * 8 + j_;                                                     \
      __builtin_amdgcn_global_load_lds(                                         \
          (const __attribute__((address_space(1))) unsigned int*)(src_ +        \
              ch_ * 1024 + laneoff),                                            \
          (__attribute__((address_space(3))) unsigned int*)(lds_ + ch_ * 1024), \
          16, 0, 0);                                                            \
    }                                                                           \
  }

#define LOAD_Q(h, a0, a1)                                                       \
  {                                                                             \
    const f16* qp_ = qs +                                                       \
        ((size_t)((b * 16 + (h)) * 1024 + q0 + w * 16 + l15)) * 64 + l4 * 8;    \
    a0 = *(const f16x8*)qp_;                                                    \
    a1 = *(const f16x8*)(qp_ + 32);                                             \
  }

  f16x8 qa0, qa1, qn0, qn1;
  STAGE_K(0, hgIdx * 8);            // 8 loads
  LOAD_Q(hgIdx * 8, qa0, qa1);      // 2 loads
  qn0 = qa0; qn1 = qa1;

  f32x4 accO[4];
#pragma unroll
  for (int i = 0; i < 4; ++i) accO[i] = (f32x4)0.f;

  // outstanding: vfrag(8) + stage(8) + Q(2); vmcnt(2) => vfrag+stage retired
  asm volatile("s_waitcnt vmcnt(2)" ::: "memory");
  __builtin_amdgcn_s_barrier();

  const int ql = w * 16 + l15;        // this lane's q row within the 64-tile
  const int swq = (ql & 7) << 4;      // P swizzle for this lane's row

#pragma unroll 1
  for (int hh = 0; hh < 8; ++hh) {
    const int h = hgIdx * 8 + hh;
    const int cur = hh & 1;
    if (hh < 7) {
      STAGE_K(cur ^ 1, h + 1);      // 8 loads (oldest of this iteration)
      LOAD_Q(h + 1, qn0, qn1);      // 2 loads
    }

    // ---- QK^T (swapped): accS[sf][r] = S[q=ql][s=sf*16+l4*4+r] ----
    f32x4 accS[16];
#pragma unroll
    for (int sf = 0; sf < 16; ++sf) accS[sf] = (f32x4)0.f;
    const char* Kc = &Kbuf[cur][0];
    {
      const int sw = (l15 & 7) << 4;
      __builtin_amdgcn_s_setprio(1);
#pragma unroll
      for (int sf = 0; sf < 16; ++sf) {
        const int rowb = (sf * 16 + l15) * 128;
        f16x8 b0 = *(const f16x8*)(Kc + rowb + ((l4 * 16) ^ sw));
        f16x8 b1 = *(const f16x8*)(Kc + rowb + ((64 + l4 * 16) ^ sw));
        accS[sf] = MFMA_F16(b0, qa0, accS[sf]);
        accS[sf] = MFMA_F16(b1, qa1, accS[sf]);
      }
      __builtin_amdgcn_s_setprio(0);
    }

    // ---- softmax: lane-local row, 2+2 shfl across l4 groups ----
    float mx = -3.0e38f;
    if (q0 < SEGW) {  // uniform: only qt<4 ever masks
      const int qg = q0 + ql;
#pragma unroll
      for (int sf = 0; sf < 16; ++sf)
#pragma unroll
        for (int r = 0; r < 4; ++r) {
          int s = sf * 16 + l4 * 4 + r;
          float vv = accS[sf][r] * 0.125f;
          if (s > qg) vv = -3.0e38f;
          accS[sf][r] = vv;
          mx = fmaxf(mx, vv);
        }
    } else {
#pragma unroll
      for (int sf = 0; sf < 16; ++sf)
#pragma unroll
        for (int r = 0; r < 4; ++r) {
          float vv = accS[sf][r] * 0.125f;
          accS[sf][r] = vv;
          mx = fmaxf(mx, vv);
        }
    }
    mx = fmaxf(mx, __shfl_xor(mx, 16));
    mx = fmaxf(mx, __shfl_xor(mx, 32));
    float sum = 0.f;
#pragma unroll
    for (int sf = 0; sf < 16; ++sf)
#pragma unroll
      for (int r = 0; r < 4; ++r) {
        float e = __expf(accS[sf][r] - mx);
        accS[sf][r] = e;
        sum += e;
      }
    sum += __shfl_xor(sum, 16);
    sum += __shfl_xor(sum, 32);
    const float inv = 1.0f / sum;

    // all waves done reading K[cur] -> safe to overlay P
    asm volatile("s_waitcnt lgkmcnt(0)" ::: "memory");
    __builtin_amdgcn_s_barrier();

    // ---- write P (f16, swizzled): 16 x ds_write_b64, 4 consecutive s ----
    char* Pc = &Kbuf[cur][0];
#pragma unroll
    for (int sf = 0; sf < 16; ++sf) {
      f16x4 p4;
      p4[0] = (f16)(accS[sf][0] * inv);
      p4[1] = (f16)(accS[sf][1] * inv);
      p4[2] = (f16)(accS[sf][2] * inv);
      p4[3] = (f16)(accS[sf][3] * inv);
      *(f16x4*)(Pc + ql * 512 + ((sf * 32 + l4 * 8) ^ swq)) = p4;
    }
    asm volatile("s_waitcnt lgkmcnt(0)" ::: "memory");
    __builtin_amdgcn_s_barrier();

    // ---- PV first: MFMAs enter the pipe; stores issue under them ----
    __builtin_amdgcn_s_setprio(1);
#pragma unroll
    for (int kc = 0; kc < 8; ++kc) {
#pragma unroll
      for (int qb = 0; qb < 4; ++qb) {
        const int qr = qb * 16 + l15;
        f16x8 pa = *(const f16x8*)(Pc + qr * 512 +
                                   ((kc * 64 + l4 * 16) ^ ((qr & 7) << 4)));
        accO[qb] = MFMA_F16(pa, vfrag[kc], accO[qb]);
      }
    }
    __builtin_amdgcn_s_setprio(0);

    // ---- attn_out: contiguous 1KB per wave-row, NT stores (16 / lane) ----
    {
      const size_t base0 =
          (((size_t)b * LTOT + (size_t)n * LQ + q0) * H_ + h) * SEGW;
#pragma unroll
      for (int it = 0; it < 16; ++it) {
        const int qr = w * 16 + it;
        f16x4 p4 =
            *(const f16x4*)(Pc + qr * 512 + ((lane * 8) ^ ((qr & 7) << 4)));
        f32x4 f;
        f[0] = (float)p4[0]; f[1] = (float)p4[1];
        f[2] = (float)p4[2]; f[3] = (float)p4[3];
        __builtin_nontemporal_store(
            f, (f32x4*)(attn_out + base0 + (size_t)qr * (H_ * SEGW) + lane * 4));
      }
    }

    qa0 = qn0; qa1 = qn1;
    // vmcnt(16): drains stage+Q, leaves this head's 16 NT stores draining
    // under head h+1's compute.
    asm volatile("s_waitcnt lgkmcnt(0)" ::: "memory");
    asm volatile("s_waitcnt vmcnt(16)" ::: "memory");
    __builtin_amdgcn_s_barrier();
  }

  // ---- epilogue: mhp[hgIdx][pair*1024 + q0 + q][dv] (f16 partial /16) ----
  {
    f16* mp = mhp + ((size_t)hgIdx * 16384 + (size_t)pair * 1024 + q0) * 64 +
              w * 16 + l15;
    const float s16 = 1.0f / 16.0f;
#pragma unroll
    for (int qb = 0; qb < 4; ++qb)
#pragma unroll
      for (int r = 0; r < 4; ++r)
        mp[(size_t)(qb * 16 + l4 * 4 + r) * 64] = (f16)(accO[qb][r] * s16);
  }
#undef STAGE_K
#undef LOAD_Q
}

// ---------------- final: outputs = (mhp0+mhp1)[16384,64] @ Wh[64,1024] -----
__global__ __launch_bounds__(256) void final_f16_kernel(
    const f16* __restrict__ mhp, const f16* __restrict__ WhT,
    float* __restrict__ outputs) {
  __shared__ __align__(16) char smemF[33792];
  f16(*Af)[72] = (f16(*)[72])smemF;
  f16(*Bf)[72] = (f16(*)[72])(smemF + 9216);
  const int m0 = blockIdx.x * 64, c0 = blockIdx.y * 128;
  const int tid = threadIdx.x, lane = tid & 63, w = tid >> 6;
  const int l15 = lane & 15, l4 = lane >> 4;
  {
    int u = tid & 7, row0 = tid >> 3;
#pragma unroll
    for (int p = 0; p < 2; ++p) {
      int r = row0 + p * 32;
      size_t mi = (size_t)(m0 + r) * 64 + u * 8;
      f16x8 a0 = *(const f16x8*)(mhp + mi);
      f16x8 a1 = *(const f16x8*)(mhp + (size_t)16384 * 64 + mi);
      *(f16x8*)&Af[r][u * 8] = a0 + a1;
    }
    int cb = tid >> 3;
#pragma unroll
    for (int p = 0; p < 4; ++p) {
      int c = cb + p * 32;
      *(f16x8*)&Bf[c][u * 8] = *(const f16x8*)(WhT + (size_t)(c0 + c) * 64 + u * 8);
    }
  }
  __syncthreads();

  f32x4 acc[8];
#pragma unroll
  for (int cf = 0; cf < 8; ++cf) acc[cf] = (f32x4)0.f;
#pragma unroll
  for (int kc = 0; kc < 2; ++kc) {
    f16x8 a8 = *(const f16x8*)&Af[w * 16 + l15][kc * 32 + l4 * 8];
#pragma unroll
    for (int cf = 0; cf < 8; ++cf) {
      f16x8 b8 = *(const f16x8*)&Bf[cf * 16 + l15][kc * 32 + l4 * 8];
      acc[cf] = MFMA_F16(a8, b8, acc[cf]);
    }
  }
  __syncthreads();  // Af/Bf reads done -> overlay staging

  // ---- coalesced outputs store via LDS repack ----
  float(*Cst)[132] = (float(*)[132])smemF;
#pragma unroll
  for (int cf = 0; cf < 8; ++cf)
#pragma unroll
    for (int r = 0; r < 4; ++r)
      Cst[w * 16 + l4 * 4 + r][cf * 16 + l15] = acc[cf][r];
  __syncthreads();
#pragma unroll
  for (int p = 0; p < 8; ++p) {
    int row = p * 8 + (tid >> 5);
    int col = (tid & 31) * 4;
    f32x4 vv = *(const f32x4*)&Cst[row][col];
    __builtin_nontemporal_store(
        vv, (f32x4*)(outputs + (size_t)(m0 + row) * 1024 + c0 + col));
  }
}

// ---------------------------------------------------------------------------
extern "C" void kernel_launch(void* const* d_in, const int* in_sizes, int n_in,
                              void* d_out, int out_size, void* d_ws,
                              size_t ws_size, hipStream_t stream) {
  const float* q  = (const float*)d_in[0];
  const float* k  = (const float*)d_in[1];
  const float* v  = (const float*)d_in[2];
  const float* Wq = (const float*)d_in[3];
  const float* bq = (const float*)d_in[4];
  const float* Wk = (const float*)d_in[5];
  const float* bk = (const float*)d_in[6];
  const float* Wv = (const float*)d_in[7];
  const float* bv = (const float*)d_in[8];
  const float* Wh = (const float*)d_in[9];

  float* outputs  = (float*)d_out;
  float* attn_out = (float*)d_out + (size_t)B_ * LTOT * D_;

  char* ws = (char*)d_ws;
  f16* WqT  = (f16*)(ws + 0);                       // 2MB
  f16* WkT  = (f16*)(ws + (2u << 20));              // 2MB
  f16* WvT  = (f16*)(ws + (4u << 20));              // 128KB
  f16* WhT  = (f16*)(ws + (4u << 20) + 131072);     // 128KB
  f16* qs   = (f16*)(ws + (4u << 20) + 262144);     // 4MB
  f16* kp   = (f16*)((char*)qs + (4u << 20));       // 8MB
  f16* vpTg = (f16*)((char*)kp + (8u << 20));       // 512KB
  f16* mhp  = (f16*)((char*)vpTg + (1u << 19));     // 4MB (2 partials)

  prep_kernel<<<dim3(544), 256, 0, stream>>>(Wq, Wk, Wv, Wh, WqT, WkT, WvT, WhT);
  proj_all_kernel<<<dim3(448), 256, 0, stream>>>(q, k, v, WqT, WkT, WvT, bq, bk,
                                                 bv, qs, kp, vpTg);
  fused_attn_kernel<<<dim3(512), 256, 0, stream>>>(qs, kp, vpTg, attn_out, mhp);
  final_f16_kernel<<<dim3(256, 8), 256, 0, stream>>>(mhp, WhT, outputs);
}